// Round 1
// baseline (663.917 us; speedup 1.0000x reference)
//
#include <hip/hip_runtime.h>
#include <math.h>

#define N_NODES 50000
#define N_EDGES 800000
#define E_TOT   (N_EDGES + N_NODES)
#define D_HID   64
#define N_CLS   40

// order-preserving float<->uint encoding for atomicMax on floats
__device__ __forceinline__ unsigned enc(float f) {
    unsigned u = __float_as_uint(f);
    return (u & 0x80000000u) ? ~u : (u | 0x80000000u);
}
__device__ __forceinline__ float dec(unsigned u) {
    return (u & 0x80000000u) ? __uint_as_float(u & 0x7fffffffu)
                             : __uint_as_float(~u);
}

// ---- detect whether edge_index arrived as int64 or int32 -------------------
__global__ void k_detect(const int* ei, int* flag) {
    __shared__ int any;
    if (threadIdx.x == 0) any = 0;
    __syncthreads();
    for (int i = threadIdx.x; i < 1024; i += blockDim.x) {
        if (ei[2 * i + 1] != 0) atomicOr(&any, 1);
    }
    __syncthreads();
    if (threadIdx.x == 0) *flag = any ? 0 : 1;  // 1 => int64 layout
}

__global__ void k_convert(const void* ei, const int* flag, int* src32, int* dst32) {
    int is64 = *flag;
    int e = blockIdx.x * blockDim.x + threadIdx.x;
    if (e >= N_EDGES) return;
    if (is64) {
        const long long* p = (const long long*)ei;
        src32[e] = (int)p[e];
        dst32[e] = (int)p[N_EDGES + e];
    } else {
        const int* p = (const int*)ei;
        src32[e] = p[e];
        dst32[e] = p[N_EDGES + e];
    }
}

// ---- h = x@W  (+ per-node attention dots alpha_s, alpha_t) -----------------
// block (64,4): one wave per row, lane = output feature.
template<int K>
__global__ void k_gemm_alpha(const float* __restrict__ x, const float* __restrict__ W,
                             const float* __restrict__ aW,
                             float* __restrict__ Wh,
                             float* __restrict__ alpha_s, float* __restrict__ alpha_t) {
    __shared__ float Wl[K * 64];
    int tid = threadIdx.y * 64 + threadIdx.x;
    for (int i = tid; i < K * 64; i += 256) Wl[i] = W[i];
    __syncthreads();
    int row = blockIdx.x * 4 + threadIdx.y;
    if (row >= N_NODES) return;
    const float* xr = x + (size_t)row * K;
    int tx = threadIdx.x;
    float acc = 0.f;
#pragma unroll 8
    for (int k = 0; k < K; ++k) acc = fmaf(xr[k], Wl[k * 64 + tx], acc);
    Wh[(size_t)row * 64 + tx] = acc;
    float ps = acc * aW[tx];
    float pt = acc * aW[64 + tx];
#pragma unroll
    for (int off = 32; off; off >>= 1) {
        ps += __shfl_xor(ps, off, 64);
        pt += __shfl_xor(pt, off, 64);
    }
    if (tx == 0) { alpha_s[row] = ps; alpha_t[row] = pt; }
}

// ---- per-layer init ---------------------------------------------------------
__global__ void k_init(unsigned* agg_u, unsigned* m_u, float* z) {
    int t = blockIdx.x * blockDim.x + threadIdx.x;
    if (t < N_NODES * 64) agg_u[t] = 0u;
    if (t < N_NODES) { m_u[t] = 0u; z[t] = 0.f; }
}

// ---- per-edge attention score + segment max --------------------------------
__global__ void k_edge_sim(const int* __restrict__ src32, const int* __restrict__ dst32,
                           const float* __restrict__ alpha_s, const float* __restrict__ alpha_t,
                           const float* __restrict__ ab,
                           float* __restrict__ simbuf, unsigned* __restrict__ m_u) {
    int e = blockIdx.x * blockDim.x + threadIdx.x;
    if (e >= E_TOT) return;
    int s, d;
    if (e < N_EDGES) { s = src32[e]; d = dst32[e]; } else { s = d = e - N_EDGES; }
    float sim = alpha_s[s] + alpha_t[d] + ab[0];
    sim = sim > 0.f ? sim : 0.2f * sim;   // leaky_relu(0.2)
    simbuf[e] = sim;
    atomicMax(&m_u[d], enc(sim));
}

// ---- per-edge exp + segment sum --------------------------------------------
__global__ void k_edge_exp(const int* __restrict__ dst32,
                           float* __restrict__ simbuf,
                           const unsigned* __restrict__ m_u, float* __restrict__ z) {
    int e = blockIdx.x * blockDim.x + threadIdx.x;
    if (e >= E_TOT) return;
    int d = (e < N_EDGES) ? dst32[e] : e - N_EDGES;
    float ee = expf(simbuf[e] - dec(m_u[d]));
    simbuf[e] = ee;
    atomicAdd(&z[d], ee);
}

// ---- per-edge scatter-max of a * h[src]  (lane = feature) ------------------
__global__ void k_edge_scatter(const int* __restrict__ src32, const int* __restrict__ dst32,
                               const float* __restrict__ simbuf, const float* __restrict__ z,
                               const float* __restrict__ Wh, unsigned* __restrict__ agg_u) {
    int t = blockIdx.x * blockDim.x + threadIdx.x;
    int e = t >> 6;
    int f = t & 63;
    if (e >= E_TOT) return;
    int s, d;
    if (e < N_EDGES) { s = src32[e]; d = dst32[e]; } else { s = d = e - N_EDGES; }
    float a = simbuf[e] / z[d];
    float val = a * Wh[(size_t)s * 64 + f];
    atomicMax(&agg_u[(size_t)d * 64 + f], enc(val));
}

// ---- decode + bias + relu ---------------------------------------------------
__global__ void k_finalize(const unsigned* __restrict__ agg_u, const float* __restrict__ bias,
                           float* __restrict__ out) {
    int t = blockIdx.x * blockDim.x + threadIdx.x;
    if (t >= N_NODES * 64) return;
    float v = dec(agg_u[t]) + bias[t & 63];
    out[t] = v > 0.f ? v : 0.f;
}

// ---- output head: logits = h@Wo + bo, row log_softmax ----------------------
__global__ void k_head(const float* __restrict__ h, const float* __restrict__ Wo,
                       const float* __restrict__ bo, float* __restrict__ out) {
    __shared__ float sh[4][64];
    int w = threadIdx.y;
    int lane = threadIdx.x;
    int row = blockIdx.x * 4 + w;
    sh[w][lane] = h[(size_t)row * 64 + lane];
    __syncthreads();
    float logit = -INFINITY;
    if (lane < N_CLS) {
        float acc = bo[lane];
#pragma unroll
        for (int k = 0; k < 64; ++k) acc = fmaf(sh[w][k], Wo[k * N_CLS + lane], acc);
        logit = acc;
    }
    float mx = logit;
#pragma unroll
    for (int off = 32; off; off >>= 1) mx = fmaxf(mx, __shfl_xor(mx, off, 64));
    float ex = (lane < N_CLS) ? expf(logit - mx) : 0.f;
    float sm = ex;
#pragma unroll
    for (int off = 32; off; off >>= 1) sm += __shfl_xor(sm, off, 64);
    float lse = mx + logf(sm);
    if (lane < N_CLS) out[(size_t)row * N_CLS + lane] = logit - lse;
}

extern "C" void kernel_launch(void* const* d_in, const int* in_sizes, int n_in,
                              void* d_out, int out_size, void* d_ws, size_t ws_size,
                              hipStream_t stream) {
    const float* x   = (const float*)d_in[0];
    const void*  ei  = d_in[1];
    const float* W1  = (const float*)d_in[2];
    const float* aW1 = (const float*)d_in[3];
    const float* ab1 = (const float*)d_in[4];
    const float* b1  = (const float*)d_in[5];
    const float* W2  = (const float*)d_in[6];
    const float* aW2 = (const float*)d_in[7];
    const float* ab2 = (const float*)d_in[8];
    const float* b2  = (const float*)d_in[9];
    const float* Wo  = (const float*)d_in[10];
    const float* bo  = (const float*)d_in[11];
    float* out = (float*)d_out;

    char* ws = (char*)d_ws;
    size_t off = 0;
    auto alloc = [&](size_t bytes) {
        void* p = ws + off;
        off += (bytes + 255) & ~(size_t)255;
        return p;
    };
    int*      src32   = (int*)alloc((size_t)N_EDGES * 4);
    int*      dst32   = (int*)alloc((size_t)N_EDGES * 4);
    float*    Wh      = (float*)alloc((size_t)N_NODES * 64 * 4);
    float*    h_mid   = (float*)alloc((size_t)N_NODES * 64 * 4);
    float*    h_fin   = (float*)alloc((size_t)N_NODES * 64 * 4);
    float*    alpha_s = (float*)alloc((size_t)N_NODES * 4);
    float*    alpha_t = (float*)alloc((size_t)N_NODES * 4);
    unsigned* m_u     = (unsigned*)alloc((size_t)N_NODES * 4);
    float*    zbuf    = (float*)alloc((size_t)N_NODES * 4);
    float*    simbuf  = (float*)alloc((size_t)E_TOT * 4);
    unsigned* agg_u   = (unsigned*)alloc((size_t)N_NODES * 64 * 4);
    int*      flag    = (int*)alloc(256);

    const int B = 256;
    int gEdge = (E_TOT + B - 1) / B;
    int gNF   = (N_NODES * 64 + B - 1) / B;
    int gScat = (E_TOT * 64 + B - 1) / B;
    int gConv = (N_EDGES + B - 1) / B;
    dim3 blk2(64, 4);
    int gRow = (N_NODES + 3) / 4;

    k_detect<<<1, 256, 0, stream>>>((const int*)ei, flag);
    k_convert<<<gConv, B, 0, stream>>>(ei, flag, src32, dst32);

    // ---- layer 1
    k_gemm_alpha<128><<<gRow, blk2, 0, stream>>>(x, W1, aW1, Wh, alpha_s, alpha_t);
    k_init<<<gNF, B, 0, stream>>>(agg_u, m_u, zbuf);
    k_edge_sim<<<gEdge, B, 0, stream>>>(src32, dst32, alpha_s, alpha_t, ab1, simbuf, m_u);
    k_edge_exp<<<gEdge, B, 0, stream>>>(dst32, simbuf, m_u, zbuf);
    k_edge_scatter<<<gScat, B, 0, stream>>>(src32, dst32, simbuf, zbuf, Wh, agg_u);
    k_finalize<<<gNF, B, 0, stream>>>(agg_u, b1, h_mid);

    // ---- layer 2
    k_gemm_alpha<64><<<gRow, blk2, 0, stream>>>(h_mid, W2, aW2, Wh, alpha_s, alpha_t);
    k_init<<<gNF, B, 0, stream>>>(agg_u, m_u, zbuf);
    k_edge_sim<<<gEdge, B, 0, stream>>>(src32, dst32, alpha_s, alpha_t, ab2, simbuf, m_u);
    k_edge_exp<<<gEdge, B, 0, stream>>>(dst32, simbuf, m_u, zbuf);
    k_edge_scatter<<<gScat, B, 0, stream>>>(src32, dst32, simbuf, zbuf, Wh, agg_u);
    k_finalize<<<gNF, B, 0, stream>>>(agg_u, b2, h_fin);

    // ---- head
    k_head<<<gRow, blk2, 0, stream>>>(h_fin, Wo, bo, out);
}

// Round 2
// 383.445 us; speedup vs baseline: 1.7314x; 1.7314x over previous
//
#include <hip/hip_runtime.h>
#include <math.h>

#define N_NODES 50000
#define N_EDGES 800000
#define E_TOT   (N_EDGES + N_NODES)
#define D_HID   64
#define N_CLS   40
#define SCAN_B  256
#define N_CHUNKS ((N_NODES + SCAN_B - 1) / SCAN_B)   // 196

// ---- detect whether edge_index arrived as int64 or int32 -------------------
__global__ void k_detect(const int* ei, int* flag) {
    __shared__ int any;
    if (threadIdx.x == 0) any = 0;
    __syncthreads();
    for (int i = threadIdx.x; i < 1024; i += blockDim.x) {
        if (ei[2 * i + 1] != 0) atomicOr(&any, 1);
    }
    __syncthreads();
    if (threadIdx.x == 0) *flag = any ? 0 : 1;  // 1 => int64 layout
}

__global__ void k_convert(const void* ei, const int* flag, int* src32, int* dst32) {
    int is64 = *flag;
    int e = blockIdx.x * blockDim.x + threadIdx.x;
    if (e >= N_EDGES) return;
    if (is64) {
        const long long* p = (const long long*)ei;
        src32[e] = (int)p[e];
        dst32[e] = (int)p[N_EDGES + e];
    } else {
        const int* p = (const int*)ei;
        src32[e] = p[e];
        dst32[e] = p[N_EDGES + e];
    }
}

// ---- CSR build: histogram -> scan -> scatter -------------------------------
__global__ void k_hist_init(int* deg) {
    int i = blockIdx.x * blockDim.x + threadIdx.x;
    if (i < N_NODES) deg[i] = 1;   // self loop
}

__global__ void k_hist(const int* __restrict__ dst32, int* __restrict__ deg) {
    int e = blockIdx.x * blockDim.x + threadIdx.x;
    if (e < N_EDGES) atomicAdd(&deg[dst32[e]], 1);
}

__device__ __forceinline__ int block_scan_incl(int v, int* wsum) {
    int lane = threadIdx.x & 63, w = threadIdx.x >> 6;
    int s = v;
#pragma unroll
    for (int d = 1; d < 64; d <<= 1) {
        int t = __shfl_up(s, d, 64);
        if (lane >= d) s += t;
    }
    if (lane == 63) wsum[w] = s;
    __syncthreads();
    int add = 0;
    for (int ww = 0; ww < (threadIdx.x >> 6); ++ww) add += wsum[ww];
    return s + add;
}

__global__ void k_scan1(const int* __restrict__ deg, int* __restrict__ rowptr,
                        int* __restrict__ partials) {
    __shared__ int wsum[4];
    int i = blockIdx.x * SCAN_B + threadIdx.x;
    int v = (i < N_NODES) ? deg[i] : 0;
    int s = block_scan_incl(v, wsum);
    if (i < N_NODES) rowptr[i] = s - v;          // block-local exclusive
    if (threadIdx.x == SCAN_B - 1) partials[blockIdx.x] = s;
}

__global__ void k_scan2(int* partials) {
    __shared__ int wsum[4];
    int i = threadIdx.x;
    int v = (i < N_CHUNKS) ? partials[i] : 0;
    int s = block_scan_incl(v, wsum);
    if (i < N_CHUNKS) partials[i] = s - v;       // exclusive
}

__global__ void k_scan3(const int* __restrict__ partials, int* __restrict__ rowptr,
                        int* __restrict__ cursor) {
    int i = blockIdx.x * SCAN_B + threadIdx.x;
    if (i < N_NODES) {
        int r = rowptr[i] + partials[blockIdx.x];
        rowptr[i] = r;
        cursor[i] = r;
    }
    if (blockIdx.x == 0 && threadIdx.x == 0) rowptr[N_NODES] = E_TOT;
}

__global__ void k_scatter_csr(const int* __restrict__ src32, const int* __restrict__ dst32,
                              int* __restrict__ cursor, int* __restrict__ src_sorted) {
    int e = blockIdx.x * blockDim.x + threadIdx.x;
    if (e >= E_TOT) return;
    int s, d;
    if (e < N_EDGES) { s = src32[e]; d = dst32[e]; } else { s = d = e - N_EDGES; }
    int pos = atomicAdd(&cursor[d], 1);
    src_sorted[pos] = s;
}

// ---- h = x@W  (+ per-node attention dots alpha_s, alpha_t) -----------------
template<int K>
__global__ void k_gemm_alpha(const float* __restrict__ x, const float* __restrict__ W,
                             const float* __restrict__ aW,
                             float* __restrict__ Wh,
                             float* __restrict__ alpha_s, float* __restrict__ alpha_t) {
    __shared__ float Wl[K * 64];
    int tid = threadIdx.y * 64 + threadIdx.x;
    for (int i = tid; i < K * 64; i += 256) Wl[i] = W[i];
    __syncthreads();
    int row = blockIdx.x * 4 + threadIdx.y;
    const float* xr = x + (size_t)row * K;
    int tx = threadIdx.x;
    float acc = 0.f;
#pragma unroll 8
    for (int k = 0; k < K; ++k) acc = fmaf(xr[k], Wl[k * 64 + tx], acc);
    Wh[(size_t)row * 64 + tx] = acc;
    float ps = acc * aW[tx];
    float pt = acc * aW[64 + tx];
#pragma unroll
    for (int off = 32; off; off >>= 1) {
        ps += __shfl_xor(ps, off, 64);
        pt += __shfl_xor(pt, off, 64);
    }
    if (tx == 0) { alpha_s[row] = ps; alpha_t[row] = pt; }
}

// ---- per-dst-node fused: attention softmax + scatter-max aggregation -------
// one wave per node, lane = feature. HEAD=0: write relu(h)+bias to outp[N,64].
// HEAD=1: fuse output head -> log_softmax -> outp[N,40].
template<int HEAD>
__global__ void k_node_aggr(const int* __restrict__ rowptr, const int* __restrict__ src_sorted,
                            const float* __restrict__ alpha_s, const float* __restrict__ alpha_t,
                            const float* __restrict__ ab, const float* __restrict__ Wh,
                            const float* __restrict__ bias,
                            const float* __restrict__ Wo, const float* __restrict__ bo,
                            float* __restrict__ outp) {
    __shared__ float sWo[HEAD ? 64 * N_CLS : 1];
    __shared__ float sh[4][64];
    int lane = threadIdx.x, w = threadIdx.y;
    if (HEAD) {
        int tid = w * 64 + lane;
        for (int i = tid; i < 64 * N_CLS; i += 256) sWo[i] = Wo[i];
        __syncthreads();
    }
    int d = blockIdx.x * 4 + w;            // grid is exact: 12500*4 == N_NODES
    int rs = rowptr[d], re = rowptr[d + 1];
    float at = alpha_t[d] + ab[0];

    // pass 1: segment max of leaky_relu scores
    float m = -INFINITY;
    for (int base = rs; base < re; base += 64) {
        int idx = base + lane;
        float sim = -INFINITY;
        if (idx < re) {
            int sv = src_sorted[idx];
            float t = alpha_s[sv] + at;
            sim = t > 0.f ? t : 0.2f * t;
        }
#pragma unroll
        for (int o = 32; o; o >>= 1) sim = fmaxf(sim, __shfl_xor(sim, o, 64));
        m = fmaxf(m, sim);
    }

    // pass 2: exp-sum z + unnormalized scatter-max of e_j * Wh[src_j]
    float z = 0.f, vmax = -INFINITY;
    for (int base = rs; base < re; base += 64) {
        int idx = base + lane;
        int cnt = min(64, re - base);
        int sv = 0;
        float ev = 0.f;
        if (idx < re) {
            sv = src_sorted[idx];
            float t = alpha_s[sv] + at;
            t = t > 0.f ? t : 0.2f * t;
            ev = expf(t - m);
        }
        float sz = ev;
#pragma unroll
        for (int o = 32; o; o >>= 1) sz += __shfl_xor(sz, o, 64);
        z += sz;
        for (int j = 0; j < cnt; ++j) {
            int sj = __shfl(sv, j, 64);
            float ej = __shfl(ev, j, 64);
            vmax = fmaxf(vmax, ej * Wh[(size_t)sj * 64 + lane]);
        }
    }
    // max(e_j/z * s_j) == max(e_j * s_j)/z since z > 0
    float h = vmax / z + bias[lane];
    h = h > 0.f ? h : 0.f;

    if (!HEAD) {
        outp[(size_t)d * 64 + lane] = h;
    } else {
        sh[w][lane] = h;
        __syncthreads();
        float logit = -INFINITY;
        if (lane < N_CLS) {
            float acc = bo[lane];
#pragma unroll
            for (int k = 0; k < 64; ++k) acc = fmaf(sh[w][k], sWo[k * N_CLS + lane], acc);
            logit = acc;
        }
        float mx = logit;
#pragma unroll
        for (int o = 32; o; o >>= 1) mx = fmaxf(mx, __shfl_xor(mx, o, 64));
        float ex = (lane < N_CLS) ? expf(logit - mx) : 0.f;
        float sm = ex;
#pragma unroll
        for (int o = 32; o; o >>= 1) sm += __shfl_xor(sm, o, 64);
        float lse = mx + logf(sm);
        if (lane < N_CLS) outp[(size_t)d * N_CLS + lane] = logit - lse;
    }
}

extern "C" void kernel_launch(void* const* d_in, const int* in_sizes, int n_in,
                              void* d_out, int out_size, void* d_ws, size_t ws_size,
                              hipStream_t stream) {
    const float* x   = (const float*)d_in[0];
    const void*  ei  = d_in[1];
    const float* W1  = (const float*)d_in[2];
    const float* aW1 = (const float*)d_in[3];
    const float* ab1 = (const float*)d_in[4];
    const float* b1  = (const float*)d_in[5];
    const float* W2  = (const float*)d_in[6];
    const float* aW2 = (const float*)d_in[7];
    const float* ab2 = (const float*)d_in[8];
    const float* b2  = (const float*)d_in[9];
    const float* Wo  = (const float*)d_in[10];
    const float* bo  = (const float*)d_in[11];
    float* out = (float*)d_out;

    char* ws = (char*)d_ws;
    size_t off = 0;
    auto alloc = [&](size_t bytes) {
        void* p = ws + off;
        off += (bytes + 255) & ~(size_t)255;
        return p;
    };
    int*   src32      = (int*)alloc((size_t)N_EDGES * 4);
    int*   dst32      = (int*)alloc((size_t)N_EDGES * 4);
    int*   deg        = (int*)alloc((size_t)N_NODES * 4);
    int*   rowptr     = (int*)alloc((size_t)(N_NODES + 1) * 4);
    int*   cursor     = (int*)alloc((size_t)N_NODES * 4);
    int*   partials   = (int*)alloc((size_t)SCAN_B * 4);
    int*   src_sorted = (int*)alloc((size_t)E_TOT * 4);
    float* Wh         = (float*)alloc((size_t)N_NODES * 64 * 4);
    float* h_mid      = (float*)alloc((size_t)N_NODES * 64 * 4);
    float* alpha_s    = (float*)alloc((size_t)N_NODES * 4);
    float* alpha_t    = (float*)alloc((size_t)N_NODES * 4);
    int*   flag       = (int*)alloc(256);

    const int B = 256;
    int gEdgeE = (N_EDGES + B - 1) / B;
    int gEdgeT = (E_TOT + B - 1) / B;
    int gNode  = (N_NODES + B - 1) / B;
    dim3 blk2(64, 4);
    int gRow = N_NODES / 4;   // 12500, exact

    // ---- CSR build
    k_detect<<<1, 256, 0, stream>>>((const int*)ei, flag);
    k_convert<<<gEdgeE, B, 0, stream>>>(ei, flag, src32, dst32);
    k_hist_init<<<gNode, B, 0, stream>>>(deg);
    k_hist<<<gEdgeE, B, 0, stream>>>(dst32, deg);
    k_scan1<<<N_CHUNKS, SCAN_B, 0, stream>>>(deg, rowptr, partials);
    k_scan2<<<1, SCAN_B, 0, stream>>>(partials);
    k_scan3<<<N_CHUNKS, SCAN_B, 0, stream>>>(partials, rowptr, cursor);
    k_scatter_csr<<<gEdgeT, B, 0, stream>>>(src32, dst32, cursor, src_sorted);

    // ---- layer 1
    k_gemm_alpha<128><<<gRow, blk2, 0, stream>>>(x, W1, aW1, Wh, alpha_s, alpha_t);
    k_node_aggr<0><<<gRow, blk2, 0, stream>>>(rowptr, src_sorted, alpha_s, alpha_t,
                                              ab1, Wh, b1, nullptr, nullptr, h_mid);

    // ---- layer 2 (+ fused output head)
    k_gemm_alpha<64><<<gRow, blk2, 0, stream>>>(h_mid, W2, aW2, Wh, alpha_s, alpha_t);
    k_node_aggr<1><<<gRow, blk2, 0, stream>>>(rowptr, src_sorted, alpha_s, alpha_t,
                                              ab2, Wh, b2, Wo, bo, out);
}

// Round 3
// 314.335 us; speedup vs baseline: 2.1121x; 1.2199x over previous
//
#include <hip/hip_runtime.h>
#include <math.h>

#define N_NODES 50000
#define N_EDGES 800000
#define E_TOT   (N_EDGES + N_NODES)
#define D_HID   64
#define N_CLS   40
#define SCAN_B  256
#define N_CHUNKS ((N_NODES + SCAN_B - 1) / SCAN_B)   // 196

// ---- detect whether edge_index arrived as int64 or int32 -------------------
__global__ void k_detect(const int* ei, int* flag) {
    __shared__ int any;
    if (threadIdx.x == 0) any = 0;
    __syncthreads();
    for (int i = threadIdx.x; i < 1024; i += blockDim.x) {
        if (ei[2 * i + 1] != 0) atomicOr(&any, 1);
    }
    __syncthreads();
    if (threadIdx.x == 0) *flag = any ? 0 : 1;  // 1 => int64 layout
}

__global__ void k_convert(const void* ei, const int* flag, int* src32, int* dst32) {
    int is64 = *flag;
    int e = blockIdx.x * blockDim.x + threadIdx.x;
    if (e >= N_EDGES) return;
    if (is64) {
        const long long* p = (const long long*)ei;
        src32[e] = (int)p[e];
        dst32[e] = (int)p[N_EDGES + e];
    } else {
        const int* p = (const int*)ei;
        src32[e] = p[e];
        dst32[e] = p[N_EDGES + e];
    }
}

// ---- CSR build: histogram -> scan -> scatter -------------------------------
__global__ void k_hist_init(int* deg) {
    int i = blockIdx.x * blockDim.x + threadIdx.x;
    if (i < N_NODES) deg[i] = 1;   // self loop
}

__global__ void k_hist(const int* __restrict__ dst32, int* __restrict__ deg) {
    int e = blockIdx.x * blockDim.x + threadIdx.x;
    if (e < N_EDGES) atomicAdd(&deg[dst32[e]], 1);
}

__device__ __forceinline__ int block_scan_incl(int v, int* wsum) {
    int lane = threadIdx.x & 63, w = threadIdx.x >> 6;
    int s = v;
#pragma unroll
    for (int d = 1; d < 64; d <<= 1) {
        int t = __shfl_up(s, d, 64);
        if (lane >= d) s += t;
    }
    if (lane == 63) wsum[w] = s;
    __syncthreads();
    int add = 0;
    for (int ww = 0; ww < (threadIdx.x >> 6); ++ww) add += wsum[ww];
    return s + add;
}

__global__ void k_scan1(const int* __restrict__ deg, int* __restrict__ rowptr,
                        int* __restrict__ partials) {
    __shared__ int wsum[4];
    int i = blockIdx.x * SCAN_B + threadIdx.x;
    int v = (i < N_NODES) ? deg[i] : 0;
    int s = block_scan_incl(v, wsum);
    if (i < N_NODES) rowptr[i] = s - v;          // block-local exclusive
    if (threadIdx.x == SCAN_B - 1) partials[blockIdx.x] = s;
}

__global__ void k_scan2(int* partials) {
    __shared__ int wsum[4];
    int i = threadIdx.x;
    int v = (i < N_CHUNKS) ? partials[i] : 0;
    int s = block_scan_incl(v, wsum);
    if (i < N_CHUNKS) partials[i] = s - v;       // exclusive
}

__global__ void k_scan3(const int* __restrict__ partials, int* __restrict__ rowptr,
                        int* __restrict__ cursor) {
    int i = blockIdx.x * SCAN_B + threadIdx.x;
    if (i < N_NODES) {
        int r = rowptr[i] + partials[blockIdx.x];
        rowptr[i] = r;
        cursor[i] = r;
    }
    if (blockIdx.x == 0 && threadIdx.x == 0) rowptr[N_NODES] = E_TOT;
}

__global__ void k_scatter_csr(const int* __restrict__ src32, const int* __restrict__ dst32,
                              int* __restrict__ cursor, int* __restrict__ src_sorted) {
    int e = blockIdx.x * blockDim.x + threadIdx.x;
    if (e >= E_TOT) return;
    int s, d;
    if (e < N_EDGES) { s = src32[e]; d = dst32[e]; } else { s = d = e - N_EDGES; }
    int pos = atomicAdd(&cursor[d], 1);
    src_sorted[pos] = s;
}

// ---- h = x@W  (+ per-node attention dots alpha_s, alpha_t) -----------------
template<int K>
__global__ void k_gemm_alpha(const float* __restrict__ x, const float* __restrict__ W,
                             const float* __restrict__ aW,
                             float* __restrict__ Wh,
                             float* __restrict__ alpha_s, float* __restrict__ alpha_t) {
    __shared__ float Wl[K * 64];
    int tid = threadIdx.y * 64 + threadIdx.x;
    for (int i = tid; i < K * 64; i += 256) Wl[i] = W[i];
    __syncthreads();
    int row = blockIdx.x * 4 + threadIdx.y;
    const float* xr = x + (size_t)row * K;
    int tx = threadIdx.x;
    float acc = 0.f;
#pragma unroll 8
    for (int k = 0; k < K; ++k) acc = fmaf(xr[k], Wl[k * 64 + tx], acc);
    Wh[(size_t)row * 64 + tx] = acc;
    float ps = acc * aW[tx];
    float pt = acc * aW[64 + tx];
#pragma unroll
    for (int off = 32; off; off >>= 1) {
        ps += __shfl_xor(ps, off, 64);
        pt += __shfl_xor(pt, off, 64);
    }
    if (tx == 0) { alpha_s[row] = ps; alpha_t[row] = pt; }
}

// ---- per-dst-node fused: attention softmax + scatter-max aggregation -------
// One wave per node. Fast path (deg<=64): lane j holds edge j's score; the
// feature gather runs 4 edges per global_load_dwordx4 (lane group g=lane>>4
// owns edge jb+g, 16 lanes x float4 cover the 256B Wh row).
template<int HEAD>
__global__ void k_node_aggr(const int* __restrict__ rowptr, const int* __restrict__ src_sorted,
                            const float* __restrict__ alpha_s, const float* __restrict__ alpha_t,
                            const float* __restrict__ ab, const float* __restrict__ Wh,
                            const float* __restrict__ bias,
                            const float* __restrict__ Wo, const float* __restrict__ bo,
                            float* __restrict__ outp) {
    __shared__ float sWo[HEAD ? 64 * N_CLS : 1];
    __shared__ float sh[HEAD ? 4 * 64 : 1];
    int lane = threadIdx.x, w = threadIdx.y;
    if (HEAD) {
        int tid = w * 64 + lane;
        for (int i = tid; i < 64 * N_CLS; i += 256) sWo[i] = Wo[i];
    }
    int d = blockIdx.x * 4 + w;            // grid exact: 12500*4 == N_NODES
    int rs = rowptr[d], re = rowptr[d + 1];
    int deg = re - rs;
    float at = alpha_t[d] + ab[0];
    int g = lane >> 4, fl = lane & 15;

    float z;
    float4 vmax = make_float4(-INFINITY, -INFINITY, -INFINITY, -INFINITY);

    if (deg <= 64) {
        // --- single-chunk fast path ---
        int sv = src_sorted[rs + min(lane, deg - 1)];
        float t = alpha_s[sv] + at;
        t = t > 0.f ? t : 0.2f * t;
        float tm = (lane < deg) ? t : -INFINITY;
#pragma unroll
        for (int o = 32; o; o >>= 1) tm = fmaxf(tm, __shfl_xor(tm, o, 64));
        float ev = expf(t - tm);               // valid for all lanes (dups never read)
        float zz = (lane < deg) ? ev : 0.f;
#pragma unroll
        for (int o = 32; o; o >>= 1) zz += __shfl_xor(zz, o, 64);
        z = zz;
        for (int jb = 0; jb < deg; jb += 16) {
#pragma unroll
            for (int b = 0; b < 4; ++b) {
                int j = jb + 4 * b + g;
                j = j < deg ? j : deg - 1;     // dup edges are no-ops under max
                int   sj = __shfl(sv, j, 64);
                float ej = __shfl(ev, j, 64);
                float4 vv = *(const float4*)(Wh + (size_t)sj * 64 + fl * 4);
                vmax.x = fmaxf(vmax.x, ej * vv.x);
                vmax.y = fmaxf(vmax.y, ej * vv.y);
                vmax.z = fmaxf(vmax.z, ej * vv.z);
                vmax.w = fmaxf(vmax.w, ej * vv.w);
            }
        }
    } else {
        // --- rare slow path: chunked two-pass, scalar gather ---
        float m = -INFINITY;
        for (int base = rs; base < re; base += 64) {
            int idx = base + lane;
            float sim = -INFINITY;
            if (idx < re) {
                int sv = src_sorted[idx];
                float t = alpha_s[sv] + at;
                sim = t > 0.f ? t : 0.2f * t;
            }
#pragma unroll
            for (int o = 32; o; o >>= 1) sim = fmaxf(sim, __shfl_xor(sim, o, 64));
            m = fmaxf(m, sim);
        }
        z = 0.f;
        float vsc = -INFINITY;
        for (int base = rs; base < re; base += 64) {
            int idx = base + lane;
            int cnt = min(64, re - base);
            int svv = 0;
            float ev = 0.f;
            if (idx < re) {
                svv = src_sorted[idx];
                float t = alpha_s[svv] + at;
                t = t > 0.f ? t : 0.2f * t;
                ev = expf(t - m);
            }
            float sz = ev;
#pragma unroll
            for (int o = 32; o; o >>= 1) sz += __shfl_xor(sz, o, 64);
            z += sz;
            for (int j = 0; j < cnt; ++j) {
                int sj = __shfl(svv, j, 64);
                float ej = __shfl(ev, j, 64);
                vsc = fmaxf(vsc, ej * Wh[(size_t)sj * 64 + lane]);
            }
        }
        // redistribute scalar (lane=feature) result into float4 layout:
        // lane holds feature `lane`; we need lane to hold features 4*fl..4*fl+3.
        vmax.x = __shfl(vsc, 4 * fl + 0, 64);
        vmax.y = __shfl(vsc, 4 * fl + 1, 64);
        vmax.z = __shfl(vsc, 4 * fl + 2, 64);
        vmax.w = __shfl(vsc, 4 * fl + 3, 64);
    }

    // combine across the 4 lane groups (fast path partials; slow path idempotent)
#pragma unroll
    for (int o = 16; o <= 32; o <<= 1) {
        vmax.x = fmaxf(vmax.x, __shfl_xor(vmax.x, o, 64));
        vmax.y = fmaxf(vmax.y, __shfl_xor(vmax.y, o, 64));
        vmax.z = fmaxf(vmax.z, __shfl_xor(vmax.z, o, 64));
        vmax.w = fmaxf(vmax.w, __shfl_xor(vmax.w, o, 64));
    }
    // max(e_j/z * s_j) == max(e_j * s_j)/z since z > 0
    float4 bb = ((const float4*)bias)[fl];
    float4 h4;
    h4.x = fmaxf(vmax.x / z + bb.x, 0.f);
    h4.y = fmaxf(vmax.y / z + bb.y, 0.f);
    h4.z = fmaxf(vmax.z / z + bb.z, 0.f);
    h4.w = fmaxf(vmax.w / z + bb.w, 0.f);

    if (!HEAD) {
        if (g == 0) ((float4*)(outp + (size_t)d * 64))[fl] = h4;
    } else {
        if (g == 0) ((float4*)(sh + w * 64))[fl] = h4;
        __syncthreads();
        float logit = -INFINITY;
        if (lane < N_CLS) {
            float acc = bo[lane];
#pragma unroll
            for (int k = 0; k < 64; ++k) acc = fmaf(sh[w * 64 + k], sWo[k * N_CLS + lane], acc);
            logit = acc;
        }
        float mx = logit;
#pragma unroll
        for (int o = 32; o; o >>= 1) mx = fmaxf(mx, __shfl_xor(mx, o, 64));
        float ex = (lane < N_CLS) ? expf(logit - mx) : 0.f;
        float sm = ex;
#pragma unroll
        for (int o = 32; o; o >>= 1) sm += __shfl_xor(sm, o, 64);
        float lse = mx + logf(sm);
        if (lane < N_CLS) outp[(size_t)d * N_CLS + lane] = logit - lse;
    }
}

extern "C" void kernel_launch(void* const* d_in, const int* in_sizes, int n_in,
                              void* d_out, int out_size, void* d_ws, size_t ws_size,
                              hipStream_t stream) {
    const float* x   = (const float*)d_in[0];
    const void*  ei  = d_in[1];
    const float* W1  = (const float*)d_in[2];
    const float* aW1 = (const float*)d_in[3];
    const float* ab1 = (const float*)d_in[4];
    const float* b1  = (const float*)d_in[5];
    const float* W2  = (const float*)d_in[6];
    const float* aW2 = (const float*)d_in[7];
    const float* ab2 = (const float*)d_in[8];
    const float* b2  = (const float*)d_in[9];
    const float* Wo  = (const float*)d_in[10];
    const float* bo  = (const float*)d_in[11];
    float* out = (float*)d_out;

    char* ws = (char*)d_ws;
    size_t off = 0;
    auto alloc = [&](size_t bytes) {
        void* p = ws + off;
        off += (bytes + 255) & ~(size_t)255;
        return p;
    };
    int*   src32      = (int*)alloc((size_t)N_EDGES * 4);
    int*   dst32      = (int*)alloc((size_t)N_EDGES * 4);
    int*   deg        = (int*)alloc((size_t)N_NODES * 4);
    int*   rowptr     = (int*)alloc((size_t)(N_NODES + 1) * 4);
    int*   cursor     = (int*)alloc((size_t)N_NODES * 4);
    int*   partials   = (int*)alloc((size_t)SCAN_B * 4);
    int*   src_sorted = (int*)alloc((size_t)E_TOT * 4);
    float* Wh         = (float*)alloc((size_t)N_NODES * 64 * 4);
    float* h_mid      = (float*)alloc((size_t)N_NODES * 64 * 4);
    float* alpha_s    = (float*)alloc((size_t)N_NODES * 4);
    float* alpha_t    = (float*)alloc((size_t)N_NODES * 4);
    int*   flag       = (int*)alloc(256);

    const int B = 256;
    int gEdgeE = (N_EDGES + B - 1) / B;
    int gEdgeT = (E_TOT + B - 1) / B;
    int gNode  = (N_NODES + B - 1) / B;
    dim3 blk2(64, 4);
    int gRow = N_NODES / 4;   // 12500, exact

    // ---- CSR build
    k_detect<<<1, 256, 0, stream>>>((const int*)ei, flag);
    k_convert<<<gEdgeE, B, 0, stream>>>(ei, flag, src32, dst32);
    k_hist_init<<<gNode, B, 0, stream>>>(deg);
    k_hist<<<gEdgeE, B, 0, stream>>>(dst32, deg);
    k_scan1<<<N_CHUNKS, SCAN_B, 0, stream>>>(deg, rowptr, partials);
    k_scan2<<<1, SCAN_B, 0, stream>>>(partials);
    k_scan3<<<N_CHUNKS, SCAN_B, 0, stream>>>(partials, rowptr, cursor);
    k_scatter_csr<<<gEdgeT, B, 0, stream>>>(src32, dst32, cursor, src_sorted);

    // ---- layer 1
    k_gemm_alpha<128><<<gRow, blk2, 0, stream>>>(x, W1, aW1, Wh, alpha_s, alpha_t);
    k_node_aggr<0><<<gRow, blk2, 0, stream>>>(rowptr, src_sorted, alpha_s, alpha_t,
                                              ab1, Wh, b1, nullptr, nullptr, h_mid);

    // ---- layer 2 (+ fused output head)
    k_gemm_alpha<64><<<gRow, blk2, 0, stream>>>(h_mid, W2, aW2, Wh, alpha_s, alpha_t);
    k_node_aggr<1><<<gRow, blk2, 0, stream>>>(rowptr, src_sorted, alpha_s, alpha_t,
                                              ab2, Wh, b2, Wo, bo, out);
}

// Round 4
// 274.330 us; speedup vs baseline: 2.4201x; 1.1458x over previous
//
#include <hip/hip_runtime.h>
#include <math.h>

#define N_NODES 50000
#define N_EDGES 800000
#define E_TOT   (N_EDGES + N_NODES)
#define D_HID   64
#define N_CLS   40
#define SCAN_B  256
#define N_CHUNKS ((N_NODES + SCAN_B - 1) / SCAN_B)   // 196

// ---- detect whether edge_index arrived as int64 or int32 -------------------
__global__ void k_detect(const int* ei, int* flag) {
    __shared__ int any;
    if (threadIdx.x == 0) any = 0;
    __syncthreads();
    for (int i = threadIdx.x; i < 1024; i += blockDim.x) {
        if (ei[2 * i + 1] != 0) atomicOr(&any, 1);
    }
    __syncthreads();
    if (threadIdx.x == 0) *flag = any ? 0 : 1;  // 1 => int64 layout
}

__global__ void k_convert(const void* ei, const int* flag, int* src32, int* dst32) {
    int is64 = *flag;
    int e = blockIdx.x * blockDim.x + threadIdx.x;
    if (e >= N_EDGES) return;
    if (is64) {
        const long long* p = (const long long*)ei;
        src32[e] = (int)p[e];
        dst32[e] = (int)p[N_EDGES + e];
    } else {
        const int* p = (const int*)ei;
        src32[e] = p[e];
        dst32[e] = p[N_EDGES + e];
    }
}

// ---- CSR build: histogram -> scan -> scatter -------------------------------
__global__ void k_hist_init(int* deg) {
    int i = blockIdx.x * blockDim.x + threadIdx.x;
    if (i < N_NODES) deg[i] = 1;   // self loop
}

__global__ void k_hist(const int* __restrict__ dst32, int* __restrict__ deg) {
    int e = blockIdx.x * blockDim.x + threadIdx.x;
    if (e < N_EDGES) atomicAdd(&deg[dst32[e]], 1);
}

__device__ __forceinline__ int block_scan_incl(int v, int* wsum) {
    int lane = threadIdx.x & 63, w = threadIdx.x >> 6;
    int s = v;
#pragma unroll
    for (int d = 1; d < 64; d <<= 1) {
        int t = __shfl_up(s, d, 64);
        if (lane >= d) s += t;
    }
    if (lane == 63) wsum[w] = s;
    __syncthreads();
    int add = 0;
    for (int ww = 0; ww < (threadIdx.x >> 6); ++ww) add += wsum[ww];
    return s + add;
}

__global__ void k_scan1(const int* __restrict__ deg, int* __restrict__ rowptr,
                        int* __restrict__ partials) {
    __shared__ int wsum[4];
    int i = blockIdx.x * SCAN_B + threadIdx.x;
    int v = (i < N_NODES) ? deg[i] : 0;
    int s = block_scan_incl(v, wsum);
    if (i < N_NODES) rowptr[i] = s - v;          // block-local exclusive
    if (threadIdx.x == SCAN_B - 1) partials[blockIdx.x] = s;
}

__global__ void k_scan2(int* partials) {
    __shared__ int wsum[4];
    int i = threadIdx.x;
    int v = (i < N_CHUNKS) ? partials[i] : 0;
    int s = block_scan_incl(v, wsum);
    if (i < N_CHUNKS) partials[i] = s - v;       // exclusive
}

__global__ void k_scan3(const int* __restrict__ partials, int* __restrict__ rowptr,
                        int* __restrict__ cursor) {
    int i = blockIdx.x * SCAN_B + threadIdx.x;
    if (i < N_NODES) {
        int r = rowptr[i] + partials[blockIdx.x];
        rowptr[i] = r;
        cursor[i] = r;
    }
    if (blockIdx.x == 0 && threadIdx.x == 0) rowptr[N_NODES] = E_TOT;
}

__global__ void k_scatter_csr(const int* __restrict__ src32, const int* __restrict__ dst32,
                              int* __restrict__ cursor, int* __restrict__ src_sorted) {
    int e = blockIdx.x * blockDim.x + threadIdx.x;
    if (e >= E_TOT) return;
    int s, d;
    if (e < N_EDGES) { s = src32[e]; d = dst32[e]; } else { s = d = e - N_EDGES; }
    int pos = atomicAdd(&cursor[d], 1);
    src_sorted[pos] = s;
}

// ---- register-tiled GEMM: Wh = x@W (+ alpha_s/alpha_t dots) ----------------
// block 256 threads -> 64 rows x 64 cols tile; thread (ty2=tid>>4, tx2=tid&15)
// owns acc[4][4]: rows ty2*4..+3, cols tx2*4..+3. W whole in LDS; x staged in
// 32-k transposed chunks xT[32][68] (pad 68 -> conflict-lean, 16B aligned).
template<int K>
__global__ __launch_bounds__(256) void k_gemm_alpha(
        const float* __restrict__ x, const float* __restrict__ W,
        const float* __restrict__ aW,
        float* __restrict__ Wh,
        float* __restrict__ alpha_s, float* __restrict__ alpha_t) {
    __shared__ float Wl[K * 64];
    __shared__ float xT[32][68];
    int tid = threadIdx.x;
    for (int i = tid; i < K * 64; i += 256) Wl[i] = W[i];
    int tx2 = tid & 15, ty2 = tid >> 4;
    int rowBase = blockIdx.x * 64;

    float acc[4][4];
#pragma unroll
    for (int r = 0; r < 4; ++r)
#pragma unroll
        for (int c = 0; c < 4; ++c) acc[r][c] = 0.f;

    int rr = tid >> 2;            // 0..63 : row this thread stages
    int kk = (tid & 3) * 8;       // 0,8,16,24 : k-offset this thread stages
    int srcRow = min(rowBase + rr, N_NODES - 1);
    const float* xrow = x + (size_t)srcRow * K;

    for (int kb = 0; kb < K; kb += 32) {
        __syncthreads();          // xT reads from previous chunk done
        float4 a0 = *(const float4*)(xrow + kb + kk);
        float4 a1 = *(const float4*)(xrow + kb + kk + 4);
        xT[kk + 0][rr] = a0.x; xT[kk + 1][rr] = a0.y;
        xT[kk + 2][rr] = a0.z; xT[kk + 3][rr] = a0.w;
        xT[kk + 4][rr] = a1.x; xT[kk + 5][rr] = a1.y;
        xT[kk + 6][rr] = a1.z; xT[kk + 7][rr] = a1.w;
        __syncthreads();
#pragma unroll
        for (int k2 = 0; k2 < 32; ++k2) {
            float4 xa = *(const float4*)&xT[k2][ty2 * 4];
            float4 wb = *(const float4*)&Wl[(kb + k2) * 64 + tx2 * 4];
            acc[0][0] = fmaf(xa.x, wb.x, acc[0][0]);
            acc[0][1] = fmaf(xa.x, wb.y, acc[0][1]);
            acc[0][2] = fmaf(xa.x, wb.z, acc[0][2]);
            acc[0][3] = fmaf(xa.x, wb.w, acc[0][3]);
            acc[1][0] = fmaf(xa.y, wb.x, acc[1][0]);
            acc[1][1] = fmaf(xa.y, wb.y, acc[1][1]);
            acc[1][2] = fmaf(xa.y, wb.z, acc[1][2]);
            acc[1][3] = fmaf(xa.y, wb.w, acc[1][3]);
            acc[2][0] = fmaf(xa.z, wb.x, acc[2][0]);
            acc[2][1] = fmaf(xa.z, wb.y, acc[2][1]);
            acc[2][2] = fmaf(xa.z, wb.z, acc[2][2]);
            acc[2][3] = fmaf(xa.z, wb.w, acc[2][3]);
            acc[3][0] = fmaf(xa.w, wb.x, acc[3][0]);
            acc[3][1] = fmaf(xa.w, wb.y, acc[3][1]);
            acc[3][2] = fmaf(xa.w, wb.z, acc[3][2]);
            acc[3][3] = fmaf(xa.w, wb.w, acc[3][3]);
        }
    }

    // epilogue: Wh store + per-row attention dots
    float4 as4 = *(const float4*)(aW + tx2 * 4);
    float4 at4 = *(const float4*)(aW + 64 + tx2 * 4);
#pragma unroll
    for (int r = 0; r < 4; ++r) {
        int row = rowBase + ty2 * 4 + r;
        if (row >= N_NODES) continue;
        float4 v;
        v.x = acc[r][0]; v.y = acc[r][1]; v.z = acc[r][2]; v.w = acc[r][3];
        *(float4*)(Wh + (size_t)row * 64 + tx2 * 4) = v;
        float ps = v.x * as4.x + v.y * as4.y + v.z * as4.z + v.w * as4.w;
        float pt = v.x * at4.x + v.y * at4.y + v.z * at4.z + v.w * at4.w;
#pragma unroll
        for (int o = 1; o < 16; o <<= 1) {
            ps += __shfl_xor(ps, o, 64);
            pt += __shfl_xor(pt, o, 64);
        }
        if (tx2 == 0) { alpha_s[row] = ps; alpha_t[row] = pt; }
    }
}

// ---- per-dst-node fused: attention softmax + scatter-max aggregation -------
template<int HEAD>
__global__ void k_node_aggr(const int* __restrict__ rowptr, const int* __restrict__ src_sorted,
                            const float* __restrict__ alpha_s, const float* __restrict__ alpha_t,
                            const float* __restrict__ ab, const float* __restrict__ Wh,
                            const float* __restrict__ bias,
                            const float* __restrict__ Wo, const float* __restrict__ bo,
                            float* __restrict__ outp) {
    __shared__ float sWo[HEAD ? 64 * N_CLS : 1];
    __shared__ float sh[HEAD ? 4 * 64 : 1];
    int lane = threadIdx.x, w = threadIdx.y;
    if (HEAD) {
        int tid = w * 64 + lane;
        for (int i = tid; i < 64 * N_CLS; i += 256) sWo[i] = Wo[i];
    }
    int d = blockIdx.x * 4 + w;            // grid exact: 12500*4 == N_NODES
    int rs = rowptr[d], re = rowptr[d + 1];
    int deg = re - rs;
    float at = alpha_t[d] + ab[0];
    int g = lane >> 4, fl = lane & 15;

    float z;
    float4 vmax = make_float4(-INFINITY, -INFINITY, -INFINITY, -INFINITY);

    if (deg <= 64) {
        // --- single-chunk fast path ---
        int sv = src_sorted[rs + min(lane, deg - 1)];
        float t = alpha_s[sv] + at;
        t = t > 0.f ? t : 0.2f * t;
        float tm = (lane < deg) ? t : -INFINITY;
#pragma unroll
        for (int o = 32; o; o >>= 1) tm = fmaxf(tm, __shfl_xor(tm, o, 64));
        float ev = expf(t - tm);               // valid for all lanes (dups never read)
        float zz = (lane < deg) ? ev : 0.f;
#pragma unroll
        for (int o = 32; o; o >>= 1) zz += __shfl_xor(zz, o, 64);
        z = zz;
        for (int jb = 0; jb < deg; jb += 16) {
#pragma unroll
            for (int b = 0; b < 4; ++b) {
                int j = jb + 4 * b + g;
                j = j < deg ? j : deg - 1;     // dup edges are no-ops under max
                int   sj = __shfl(sv, j, 64);
                float ej = __shfl(ev, j, 64);
                float4 vv = *(const float4*)(Wh + (size_t)sj * 64 + fl * 4);
                vmax.x = fmaxf(vmax.x, ej * vv.x);
                vmax.y = fmaxf(vmax.y, ej * vv.y);
                vmax.z = fmaxf(vmax.z, ej * vv.z);
                vmax.w = fmaxf(vmax.w, ej * vv.w);
            }
        }
    } else {
        // --- rare slow path: chunked two-pass, scalar gather ---
        float m = -INFINITY;
        for (int base = rs; base < re; base += 64) {
            int idx = base + lane;
            float sim = -INFINITY;
            if (idx < re) {
                int sv = src_sorted[idx];
                float t = alpha_s[sv] + at;
                sim = t > 0.f ? t : 0.2f * t;
            }
#pragma unroll
            for (int o = 32; o; o >>= 1) sim = fmaxf(sim, __shfl_xor(sim, o, 64));
            m = fmaxf(m, sim);
        }
        z = 0.f;
        float vsc = -INFINITY;
        for (int base = rs; base < re; base += 64) {
            int idx = base + lane;
            int cnt = min(64, re - base);
            int svv = 0;
            float ev = 0.f;
            if (idx < re) {
                svv = src_sorted[idx];
                float t = alpha_s[svv] + at;
                t = t > 0.f ? t : 0.2f * t;
                ev = expf(t - m);
            }
            float sz = ev;
#pragma unroll
            for (int o = 32; o; o >>= 1) sz += __shfl_xor(sz, o, 64);
            z += sz;
            for (int j = 0; j < cnt; ++j) {
                int sj = __shfl(svv, j, 64);
                float ej = __shfl(ev, j, 64);
                vsc = fmaxf(vsc, ej * Wh[(size_t)sj * 64 + lane]);
            }
        }
        vmax.x = __shfl(vsc, 4 * fl + 0, 64);
        vmax.y = __shfl(vsc, 4 * fl + 1, 64);
        vmax.z = __shfl(vsc, 4 * fl + 2, 64);
        vmax.w = __shfl(vsc, 4 * fl + 3, 64);
    }

    // combine across the 4 lane groups (fast path partials; slow path idempotent)
#pragma unroll
    for (int o = 16; o <= 32; o <<= 1) {
        vmax.x = fmaxf(vmax.x, __shfl_xor(vmax.x, o, 64));
        vmax.y = fmaxf(vmax.y, __shfl_xor(vmax.y, o, 64));
        vmax.z = fmaxf(vmax.z, __shfl_xor(vmax.z, o, 64));
        vmax.w = fmaxf(vmax.w, __shfl_xor(vmax.w, o, 64));
    }
    // max(e_j/z * s_j) == max(e_j * s_j)/z since z > 0
    float4 bb = ((const float4*)bias)[fl];
    float4 h4;
    h4.x = fmaxf(vmax.x / z + bb.x, 0.f);
    h4.y = fmaxf(vmax.y / z + bb.y, 0.f);
    h4.z = fmaxf(vmax.z / z + bb.z, 0.f);
    h4.w = fmaxf(vmax.w / z + bb.w, 0.f);

    if (!HEAD) {
        if (g == 0) ((float4*)(outp + (size_t)d * 64))[fl] = h4;
    } else {
        if (g == 0) ((float4*)(sh + w * 64))[fl] = h4;
        __syncthreads();
        float logit = -INFINITY;
        if (lane < N_CLS) {
            float acc = bo[lane];
#pragma unroll
            for (int k = 0; k < 64; ++k) acc = fmaf(sh[w * 64 + k], sWo[k * N_CLS + lane], acc);
            logit = acc;
        }
        float mx = logit;
#pragma unroll
        for (int o = 32; o; o >>= 1) mx = fmaxf(mx, __shfl_xor(mx, o, 64));
        float ex = (lane < N_CLS) ? expf(logit - mx) : 0.f;
        float sm = ex;
#pragma unroll
        for (int o = 32; o; o >>= 1) sm += __shfl_xor(sm, o, 64);
        float lse = mx + logf(sm);
        if (lane < N_CLS) outp[(size_t)d * N_CLS + lane] = logit - lse;
    }
}

extern "C" void kernel_launch(void* const* d_in, const int* in_sizes, int n_in,
                              void* d_out, int out_size, void* d_ws, size_t ws_size,
                              hipStream_t stream) {
    const float* x   = (const float*)d_in[0];
    const void*  ei  = d_in[1];
    const float* W1  = (const float*)d_in[2];
    const float* aW1 = (const float*)d_in[3];
    const float* ab1 = (const float*)d_in[4];
    const float* b1  = (const float*)d_in[5];
    const float* W2  = (const float*)d_in[6];
    const float* aW2 = (const float*)d_in[7];
    const float* ab2 = (const float*)d_in[8];
    const float* b2  = (const float*)d_in[9];
    const float* Wo  = (const float*)d_in[10];
    const float* bo  = (const float*)d_in[11];
    float* out = (float*)d_out;

    char* ws = (char*)d_ws;
    size_t off = 0;
    auto alloc = [&](size_t bytes) {
        void* p = ws + off;
        off += (bytes + 255) & ~(size_t)255;
        return p;
    };
    int*   src32      = (int*)alloc((size_t)N_EDGES * 4);
    int*   dst32      = (int*)alloc((size_t)N_EDGES * 4);
    int*   deg        = (int*)alloc((size_t)N_NODES * 4);
    int*   rowptr     = (int*)alloc((size_t)(N_NODES + 1) * 4);
    int*   cursor     = (int*)alloc((size_t)N_NODES * 4);
    int*   partials   = (int*)alloc((size_t)SCAN_B * 4);
    int*   src_sorted = (int*)alloc((size_t)E_TOT * 4);
    float* Wh         = (float*)alloc((size_t)N_NODES * 64 * 4);
    float* h_mid      = (float*)alloc((size_t)N_NODES * 64 * 4);
    float* alpha_s    = (float*)alloc((size_t)N_NODES * 4);
    float* alpha_t    = (float*)alloc((size_t)N_NODES * 4);
    int*   flag       = (int*)alloc(256);

    const int B = 256;
    int gEdgeE = (N_EDGES + B - 1) / B;
    int gEdgeT = (E_TOT + B - 1) / B;
    int gNode  = (N_NODES + B - 1) / B;
    dim3 blk2(64, 4);
    int gRow  = N_NODES / 4;            // 12500, exact
    int gGemm = (N_NODES + 63) / 64;    // 782

    // ---- CSR build
    k_detect<<<1, 256, 0, stream>>>((const int*)ei, flag);
    k_convert<<<gEdgeE, B, 0, stream>>>(ei, flag, src32, dst32);
    k_hist_init<<<gNode, B, 0, stream>>>(deg);
    k_hist<<<gEdgeE, B, 0, stream>>>(dst32, deg);
    k_scan1<<<N_CHUNKS, SCAN_B, 0, stream>>>(deg, rowptr, partials);
    k_scan2<<<1, SCAN_B, 0, stream>>>(partials);
    k_scan3<<<N_CHUNKS, SCAN_B, 0, stream>>>(partials, rowptr, cursor);
    k_scatter_csr<<<gEdgeT, B, 0, stream>>>(src32, dst32, cursor, src_sorted);

    // ---- layer 1
    k_gemm_alpha<128><<<gGemm, 256, 0, stream>>>(x, W1, aW1, Wh, alpha_s, alpha_t);
    k_node_aggr<0><<<gRow, blk2, 0, stream>>>(rowptr, src_sorted, alpha_s, alpha_t,
                                              ab1, Wh, b1, nullptr, nullptr, h_mid);

    // ---- layer 2 (+ fused output head)
    k_gemm_alpha<64><<<gGemm, 256, 0, stream>>>(h_mid, W2, aW2, Wh, alpha_s, alpha_t);
    k_node_aggr<1><<<gRow, blk2, 0, stream>>>(rowptr, src_sorted, alpha_s, alpha_t,
                                              ab2, Wh, b2, Wo, bo, out);
}

// Round 5
// 247.154 us; speedup vs baseline: 2.6863x; 1.1100x over previous
//
#include <hip/hip_runtime.h>
#include <hip/hip_fp16.h>
#include <math.h>

#define N_NODES 50000
#define N_EDGES 800000
#define E_TOT   (N_EDGES + N_NODES)
#define D_HID   64
#define N_CLS   40
#define SCAN_B  256
#define N_CHUNKS ((N_NODES + SCAN_B - 1) / SCAN_B)   // 196

struct __align__(8) H4 { __half2 a, b; };   // 4 halves = 8 bytes

// ---- convert (+ inline dtype detect, + degree histogram) -------------------
// Each block independently probes the first 256 int32 odd positions: for int64
// input they are all hi-words == 0; for int32 they are random node ids.
__global__ void k_convert(const void* ei, int* __restrict__ src32,
                          int* __restrict__ dst32, int* __restrict__ deg) {
    __shared__ int s_is32;
    if (threadIdx.x == 0) s_is32 = 0;
    __syncthreads();
    const int* p32 = (const int*)ei;
    if (p32[2 * threadIdx.x + 1] != 0) atomicOr(&s_is32, 1);
    __syncthreads();
    int e = blockIdx.x * 256 + threadIdx.x;
    if (e >= N_EDGES) return;
    int s, d;
    if (s_is32) {
        s = p32[e]; d = p32[N_EDGES + e];
    } else {
        const long long* p64 = (const long long*)ei;
        s = (int)p64[e]; d = (int)p64[N_EDGES + e];
    }
    src32[e] = s; dst32[e] = d;
    atomicAdd(&deg[d], 1);
}

// ---- CSR build: scan -> scatter --------------------------------------------
__device__ __forceinline__ int block_scan_incl(int v, int* wsum) {
    int lane = threadIdx.x & 63, w = threadIdx.x >> 6;
    int s = v;
#pragma unroll
    for (int d = 1; d < 64; d <<= 1) {
        int t = __shfl_up(s, d, 64);
        if (lane >= d) s += t;
    }
    if (lane == 63) wsum[w] = s;
    __syncthreads();
    int add = 0;
    for (int ww = 0; ww < (threadIdx.x >> 6); ++ww) add += wsum[ww];
    return s + add;
}

__global__ void k_scan1(const int* __restrict__ deg, int* __restrict__ rowptr,
                        int* __restrict__ partials) {
    __shared__ int wsum[4];
    int i = blockIdx.x * SCAN_B + threadIdx.x;
    int v = (i < N_NODES) ? deg[i] + 1 : 0;      // +1 = self loop
    int s = block_scan_incl(v, wsum);
    if (i < N_NODES) rowptr[i] = s - v;          // block-local exclusive
    if (threadIdx.x == SCAN_B - 1) partials[blockIdx.x] = s;
}

__global__ void k_scan2(int* partials) {
    __shared__ int wsum[4];
    int i = threadIdx.x;
    int v = (i < N_CHUNKS) ? partials[i] : 0;
    int s = block_scan_incl(v, wsum);
    if (i < N_CHUNKS) partials[i] = s - v;       // exclusive
}

__global__ void k_scan3(const int* __restrict__ partials, int* __restrict__ rowptr,
                        int* __restrict__ cursor) {
    int i = blockIdx.x * SCAN_B + threadIdx.x;
    if (i < N_NODES) {
        int r = rowptr[i] + partials[blockIdx.x];
        rowptr[i] = r;
        cursor[i] = r;
    }
    if (blockIdx.x == 0 && threadIdx.x == 0) rowptr[N_NODES] = E_TOT;
}

__global__ void k_scatter_csr(const int* __restrict__ src32, const int* __restrict__ dst32,
                              int* __restrict__ cursor, int* __restrict__ src_sorted) {
    int e = blockIdx.x * blockDim.x + threadIdx.x;
    if (e >= E_TOT) return;
    int s, d;
    if (e < N_EDGES) { s = src32[e]; d = dst32[e]; } else { s = d = e - N_EDGES; }
    int pos = atomicAdd(&cursor[d], 1);
    src_sorted[pos] = s;
}

// ---- register-tiled GEMM: WhH(fp16) = x@W (+ alpha_s/alpha_t dots) ---------
template<int K>
__global__ __launch_bounds__(256) void k_gemm_alpha(
        const float* __restrict__ x, const float* __restrict__ W,
        const float* __restrict__ aW,
        H4* __restrict__ WhH,
        float* __restrict__ alpha_s, float* __restrict__ alpha_t) {
    __shared__ float Wl[K * 64];
    __shared__ float xT[32][68];
    int tid = threadIdx.x;
    for (int i = tid; i < K * 64; i += 256) Wl[i] = W[i];
    int tx2 = tid & 15, ty2 = tid >> 4;
    int rowBase = blockIdx.x * 64;

    float acc[4][4];
#pragma unroll
    for (int r = 0; r < 4; ++r)
#pragma unroll
        for (int c = 0; c < 4; ++c) acc[r][c] = 0.f;

    int rr = tid >> 2;            // 0..63 : row this thread stages
    int kk = (tid & 3) * 8;       // 0,8,16,24 : k-offset this thread stages
    int srcRow = min(rowBase + rr, N_NODES - 1);
    const float* xrow = x + (size_t)srcRow * K;

    for (int kb = 0; kb < K; kb += 32) {
        __syncthreads();
        float4 a0 = *(const float4*)(xrow + kb + kk);
        float4 a1 = *(const float4*)(xrow + kb + kk + 4);
        xT[kk + 0][rr] = a0.x; xT[kk + 1][rr] = a0.y;
        xT[kk + 2][rr] = a0.z; xT[kk + 3][rr] = a0.w;
        xT[kk + 4][rr] = a1.x; xT[kk + 5][rr] = a1.y;
        xT[kk + 6][rr] = a1.z; xT[kk + 7][rr] = a1.w;
        __syncthreads();
#pragma unroll
        for (int k2 = 0; k2 < 32; ++k2) {
            float4 xa = *(const float4*)&xT[k2][ty2 * 4];
            float4 wb = *(const float4*)&Wl[(kb + k2) * 64 + tx2 * 4];
            acc[0][0] = fmaf(xa.x, wb.x, acc[0][0]);
            acc[0][1] = fmaf(xa.x, wb.y, acc[0][1]);
            acc[0][2] = fmaf(xa.x, wb.z, acc[0][2]);
            acc[0][3] = fmaf(xa.x, wb.w, acc[0][3]);
            acc[1][0] = fmaf(xa.y, wb.x, acc[1][0]);
            acc[1][1] = fmaf(xa.y, wb.y, acc[1][1]);
            acc[1][2] = fmaf(xa.y, wb.z, acc[1][2]);
            acc[1][3] = fmaf(xa.y, wb.w, acc[1][3]);
            acc[2][0] = fmaf(xa.z, wb.x, acc[2][0]);
            acc[2][1] = fmaf(xa.z, wb.y, acc[2][1]);
            acc[2][2] = fmaf(xa.z, wb.z, acc[2][2]);
            acc[2][3] = fmaf(xa.z, wb.w, acc[2][3]);
            acc[3][0] = fmaf(xa.w, wb.x, acc[3][0]);
            acc[3][1] = fmaf(xa.w, wb.y, acc[3][1]);
            acc[3][2] = fmaf(xa.w, wb.z, acc[3][2]);
            acc[3][3] = fmaf(xa.w, wb.w, acc[3][3]);
        }
    }

    // epilogue: fp16 Wh store + per-row attention dots (f32)
    float4 as4 = *(const float4*)(aW + tx2 * 4);
    float4 at4 = *(const float4*)(aW + 64 + tx2 * 4);
#pragma unroll
    for (int r = 0; r < 4; ++r) {
        int row = rowBase + ty2 * 4 + r;
        if (row >= N_NODES) continue;
        H4 hv;
        hv.a = __floats2half2_rn(acc[r][0], acc[r][1]);
        hv.b = __floats2half2_rn(acc[r][2], acc[r][3]);
        WhH[(size_t)row * 16 + tx2] = hv;
        float ps = acc[r][0] * as4.x + acc[r][1] * as4.y + acc[r][2] * as4.z + acc[r][3] * as4.w;
        float pt = acc[r][0] * at4.x + acc[r][1] * at4.y + acc[r][2] * at4.z + acc[r][3] * at4.w;
#pragma unroll
        for (int o = 1; o < 16; o <<= 1) {
            ps += __shfl_xor(ps, o, 64);
            pt += __shfl_xor(pt, o, 64);
        }
        if (tx2 == 0) { alpha_s[row] = ps; alpha_t[row] = pt; }
    }
}

// ---- per-dst-node fused: attention softmax + scatter-max aggregation -------
// One wave per node. Fast path (deg<=64): no max-subtract (|sim| is O(1) by
// construction; e/z is scale-invariant), (src,ev) staged in LDS as float2 and
// broadcast-read per 16-lane group; fp16 Wh gather 8B/lane (128B/row/group).
template<int HEAD>
__global__ void k_node_aggr(const int* __restrict__ rowptr, const int* __restrict__ src_sorted,
                            const float* __restrict__ alpha_s, const float* __restrict__ alpha_t,
                            const float* __restrict__ ab, const H4* __restrict__ WhH,
                            const float* __restrict__ bias,
                            const float* __restrict__ Wo, const float* __restrict__ bo,
                            float* __restrict__ outp) {
    __shared__ float sWo[HEAD ? 64 * N_CLS : 1];
    __shared__ float sh[HEAD ? 4 * 64 : 1];
    __shared__ float2 pairs[4][64];
    int lane = threadIdx.x, w = threadIdx.y;
    if (HEAD) {
        int tid = w * 64 + lane;
        for (int i = tid; i < 64 * N_CLS; i += 256) sWo[i] = Wo[i];
    }
    int d = blockIdx.x * 4 + w;            // grid exact: 12500*4 == N_NODES
    int rs = rowptr[d], re = rowptr[d + 1];
    int deg = re - rs;
    float at = alpha_t[d] + ab[0];
    int g = lane >> 4, fl = lane & 15;

    float z;
    float4 vmax = make_float4(-INFINITY, -INFINITY, -INFINITY, -INFINITY);

    if (deg <= 64) {
        // --- single-chunk fast path ---
        int sv = src_sorted[rs + min(lane, deg - 1)];
        float t = alpha_s[sv] + at;
        t = t > 0.f ? t : 0.2f * t;
        float ev = expf(t);                    // no max-subtract: |t| is O(1)
        float zz = (lane < deg) ? ev : 0.f;
#pragma unroll
        for (int o = 32; o; o >>= 1) zz += __shfl_xor(zz, o, 64);
        z = zz;
        pairs[w][lane] = make_float2(__int_as_float(sv), ev);
        for (int jb = 0; jb < deg; jb += 16) {
#pragma unroll
            for (int b = 0; b < 4; ++b) {
                int j = jb + 4 * b + g;
                j = j < deg ? j : deg - 1;     // dup edges are no-ops under max
                float2 pe = pairs[w][j];       // uniform in group -> broadcast
                int   sj = __float_as_int(pe.x);
                float ej = pe.y;
                H4 hv = WhH[(size_t)sj * 16 + fl];
                float2 fa = __half22float2(hv.a);
                float2 fb = __half22float2(hv.b);
                vmax.x = fmaxf(vmax.x, ej * fa.x);
                vmax.y = fmaxf(vmax.y, ej * fa.y);
                vmax.z = fmaxf(vmax.z, ej * fb.x);
                vmax.w = fmaxf(vmax.w, ej * fb.y);
            }
        }
    } else {
        // --- rare slow path: chunked two-pass, scalar fp16 gather ---
        float m = -INFINITY;
        for (int base = rs; base < re; base += 64) {
            int idx = base + lane;
            float sim = -INFINITY;
            if (idx < re) {
                int sv = src_sorted[idx];
                float t = alpha_s[sv] + at;
                sim = t > 0.f ? t : 0.2f * t;
            }
#pragma unroll
            for (int o = 32; o; o >>= 1) sim = fmaxf(sim, __shfl_xor(sim, o, 64));
            m = fmaxf(m, sim);
        }
        z = 0.f;
        float vsc = -INFINITY;
        for (int base = rs; base < re; base += 64) {
            int idx = base + lane;
            int cnt = min(64, re - base);
            int svv = 0;
            float ev = 0.f;
            if (idx < re) {
                svv = src_sorted[idx];
                float t = alpha_s[svv] + at;
                t = t > 0.f ? t : 0.2f * t;
                ev = expf(t - m);
            }
            float sz = ev;
#pragma unroll
            for (int o = 32; o; o >>= 1) sz += __shfl_xor(sz, o, 64);
            z += sz;
            for (int j = 0; j < cnt; ++j) {
                int sj = __shfl(svv, j, 64);
                float ej = __shfl(ev, j, 64);
                float v = __half2float(((const __half*)WhH)[(size_t)sj * 64 + lane]);
                vsc = fmaxf(vsc, ej * v);
            }
        }
        vmax.x = __shfl(vsc, 4 * fl + 0, 64);
        vmax.y = __shfl(vsc, 4 * fl + 1, 64);
        vmax.z = __shfl(vsc, 4 * fl + 2, 64);
        vmax.w = __shfl(vsc, 4 * fl + 3, 64);
    }

    // combine across the 4 lane groups (fast path partials; slow path idempotent)
#pragma unroll
    for (int o = 16; o <= 32; o <<= 1) {
        vmax.x = fmaxf(vmax.x, __shfl_xor(vmax.x, o, 64));
        vmax.y = fmaxf(vmax.y, __shfl_xor(vmax.y, o, 64));
        vmax.z = fmaxf(vmax.z, __shfl_xor(vmax.z, o, 64));
        vmax.w = fmaxf(vmax.w, __shfl_xor(vmax.w, o, 64));
    }
    // max(e_j/z * s_j) == max(e_j * s_j)/z since z > 0
    float4 bb = ((const float4*)bias)[fl];
    float4 h4;
    h4.x = fmaxf(vmax.x / z + bb.x, 0.f);
    h4.y = fmaxf(vmax.y / z + bb.y, 0.f);
    h4.z = fmaxf(vmax.z / z + bb.z, 0.f);
    h4.w = fmaxf(vmax.w / z + bb.w, 0.f);

    if (!HEAD) {
        if (g == 0) ((float4*)(outp + (size_t)d * 64))[fl] = h4;
    } else {
        if (g == 0) ((float4*)(sh + w * 64))[fl] = h4;
        __syncthreads();
        float logit = -INFINITY;
        if (lane < N_CLS) {
            float acc = bo[lane];
#pragma unroll
            for (int k = 0; k < 64; ++k) acc = fmaf(sh[w * 64 + k], sWo[k * N_CLS + lane], acc);
            logit = acc;
        }
        float mx = logit;
#pragma unroll
        for (int o = 32; o; o >>= 1) mx = fmaxf(mx, __shfl_xor(mx, o, 64));
        float ex = (lane < N_CLS) ? expf(logit - mx) : 0.f;
        float sm = ex;
#pragma unroll
        for (int o = 32; o; o >>= 1) sm += __shfl_xor(sm, o, 64);
        float lse = mx + logf(sm);
        if (lane < N_CLS) outp[(size_t)d * N_CLS + lane] = logit - lse;
    }
}

extern "C" void kernel_launch(void* const* d_in, const int* in_sizes, int n_in,
                              void* d_out, int out_size, void* d_ws, size_t ws_size,
                              hipStream_t stream) {
    const float* x   = (const float*)d_in[0];
    const void*  ei  = d_in[1];
    const float* W1  = (const float*)d_in[2];
    const float* aW1 = (const float*)d_in[3];
    const float* ab1 = (const float*)d_in[4];
    const float* b1  = (const float*)d_in[5];
    const float* W2  = (const float*)d_in[6];
    const float* aW2 = (const float*)d_in[7];
    const float* ab2 = (const float*)d_in[8];
    const float* b2  = (const float*)d_in[9];
    const float* Wo  = (const float*)d_in[10];
    const float* bo  = (const float*)d_in[11];
    float* out = (float*)d_out;

    char* ws = (char*)d_ws;
    size_t off = 0;
    auto alloc = [&](size_t bytes) {
        void* p = ws + off;
        off += (bytes + 255) & ~(size_t)255;
        return p;
    };
    int*   src32      = (int*)alloc((size_t)N_EDGES * 4);
    int*   dst32      = (int*)alloc((size_t)N_EDGES * 4);
    int*   deg        = (int*)alloc((size_t)N_NODES * 4);
    int*   rowptr     = (int*)alloc((size_t)(N_NODES + 1) * 4);
    int*   cursor     = (int*)alloc((size_t)N_NODES * 4);
    int*   partials   = (int*)alloc((size_t)SCAN_B * 4);
    int*   src_sorted = (int*)alloc((size_t)E_TOT * 4);
    H4*    WhH        = (H4*)alloc((size_t)N_NODES * 64 * 2);
    float* h_mid      = (float*)alloc((size_t)N_NODES * 64 * 4);
    float* alpha_s    = (float*)alloc((size_t)N_NODES * 4);
    float* alpha_t    = (float*)alloc((size_t)N_NODES * 4);

    const int B = 256;
    int gEdgeE = (N_EDGES + B - 1) / B;
    int gEdgeT = (E_TOT + B - 1) / B;
    dim3 blk2(64, 4);
    int gRow  = N_NODES / 4;            // 12500, exact
    int gGemm = (N_NODES + 63) / 64;    // 782

    // ---- CSR build
    hipMemsetAsync(deg, 0, (size_t)N_NODES * 4, stream);
    k_convert<<<gEdgeE, B, 0, stream>>>(ei, src32, dst32, deg);
    k_scan1<<<N_CHUNKS, SCAN_B, 0, stream>>>(deg, rowptr, partials);
    k_scan2<<<1, SCAN_B, 0, stream>>>(partials);
    k_scan3<<<N_CHUNKS, SCAN_B, 0, stream>>>(partials, rowptr, cursor);
    k_scatter_csr<<<gEdgeT, B, 0, stream>>>(src32, dst32, cursor, src_sorted);

    // ---- layer 1
    k_gemm_alpha<128><<<gGemm, 256, 0, stream>>>(x, W1, aW1, WhH, alpha_s, alpha_t);
    k_node_aggr<0><<<gRow, blk2, 0, stream>>>(rowptr, src_sorted, alpha_s, alpha_t,
                                              ab1, WhH, b1, nullptr, nullptr, h_mid);

    // ---- layer 2 (+ fused output head)
    k_gemm_alpha<64><<<gGemm, 256, 0, stream>>>(h_mid, W2, aW2, WhH, alpha_s, alpha_t);
    k_node_aggr<1><<<gRow, blk2, 0, stream>>>(rowptr, src_sorted, alpha_s, alpha_t,
                                              ab2, WhH, b2, Wo, bo, out);
}

// Round 6
// 220.925 us; speedup vs baseline: 3.0052x; 1.1187x over previous
//
#include <hip/hip_runtime.h>
#include <hip/hip_fp16.h>
#include <math.h>

#define N_NODES 50000
#define N_EDGES 800000
#define E_TOT   (N_EDGES + N_NODES)
#define D_HID   64
#define N_CLS   40
#define SCAN_B  256
#define N_CHUNKS ((N_NODES + SCAN_B - 1) / SCAN_B)   // 196

struct __align__(8) H4 { __half2 a, b; };   // 4 halves = 8 bytes

// ---- convert (+ inline dtype detect, + degree histogram) -------------------
__global__ void k_convert(const void* ei, int* __restrict__ src32,
                          int* __restrict__ dst32, int* __restrict__ deg) {
    __shared__ int s_is32;
    if (threadIdx.x == 0) s_is32 = 0;
    __syncthreads();
    const int* p32 = (const int*)ei;
    if (p32[2 * threadIdx.x + 1] != 0) atomicOr(&s_is32, 1);
    __syncthreads();
    int e = blockIdx.x * 256 + threadIdx.x;
    if (e >= N_EDGES) return;
    int s, d;
    if (s_is32) {
        s = p32[e]; d = p32[N_EDGES + e];
    } else {
        const long long* p64 = (const long long*)ei;
        s = (int)p64[e]; d = (int)p64[N_EDGES + e];
    }
    src32[e] = s; dst32[e] = d;
    atomicAdd(&deg[d], 1);
}

// ---- CSR build: scan -> scatter --------------------------------------------
__device__ __forceinline__ int block_scan_incl(int v, int* wsum) {
    int lane = threadIdx.x & 63, w = threadIdx.x >> 6;
    int s = v;
#pragma unroll
    for (int d = 1; d < 64; d <<= 1) {
        int t = __shfl_up(s, d, 64);
        if (lane >= d) s += t;
    }
    if (lane == 63) wsum[w] = s;
    __syncthreads();
    int add = 0;
    for (int ww = 0; ww < (threadIdx.x >> 6); ++ww) add += wsum[ww];
    return s + add;
}

__global__ void k_scan1(const int* __restrict__ deg, int* __restrict__ rowptr,
                        int* __restrict__ partials) {
    __shared__ int wsum[4];
    int i = blockIdx.x * SCAN_B + threadIdx.x;
    int v = (i < N_NODES) ? deg[i] + 1 : 0;      // +1 = self loop
    int s = block_scan_incl(v, wsum);
    if (i < N_NODES) rowptr[i] = s - v;          // block-local exclusive
    if (threadIdx.x == SCAN_B - 1) partials[blockIdx.x] = s;
}

__global__ void k_scan2(int* partials) {
    __shared__ int wsum[4];
    int i = threadIdx.x;
    int v = (i < N_CHUNKS) ? partials[i] : 0;
    int s = block_scan_incl(v, wsum);
    if (i < N_CHUNKS) partials[i] = s - v;       // exclusive
}

__global__ void k_scan3(const int* __restrict__ partials, int* __restrict__ rowptr,
                        int* __restrict__ cursor) {
    int i = blockIdx.x * SCAN_B + threadIdx.x;
    if (i < N_NODES) {
        int r = rowptr[i] + partials[blockIdx.x];
        rowptr[i] = r;
        cursor[i] = r;
    }
    if (blockIdx.x == 0 && threadIdx.x == 0) rowptr[N_NODES] = E_TOT;
}

__global__ void k_scatter_csr(const int* __restrict__ src32, const int* __restrict__ dst32,
                              int* __restrict__ cursor, int* __restrict__ src_sorted) {
    int e = blockIdx.x * blockDim.x + threadIdx.x;
    if (e >= E_TOT) return;
    int s, d;
    if (e < N_EDGES) { s = src32[e]; d = dst32[e]; } else { s = d = e - N_EDGES; }
    int pos = atomicAdd(&cursor[d], 1);
    src_sorted[pos] = s;
}

// ---- register-tiled GEMM: WhH(fp16) = x@W (+ alpha_s/alpha_t dots) ---------
// 256 threads -> 64x64 tile, thread owns 4x4. Both operands staged per-32-k
// chunk (17KB LDS). unroll 8 caps in-flight ds_reads (VGPR blowup fix);
// __launch_bounds__(256,4) pins allocation at <=128 VGPR.
template<int K>
__global__ __launch_bounds__(256, 4) void k_gemm_alpha(
        const float* __restrict__ x, const float* __restrict__ W,
        const float* __restrict__ aW,
        H4* __restrict__ WhH,
        float* __restrict__ alpha_s, float* __restrict__ alpha_t) {
    __shared__ float Wc[32][68];
    __shared__ float xT[32][68];
    int tid = threadIdx.x;
    int tx2 = tid & 15, ty2 = tid >> 4;
    int rowBase = blockIdx.x * 64;

    float acc[4][4];
#pragma unroll
    for (int r = 0; r < 4; ++r)
#pragma unroll
        for (int c = 0; c < 4; ++c) acc[r][c] = 0.f;

    int rr = tid >> 2;            // 0..63 : x row this thread stages
    int kk = (tid & 3) * 8;       // 0,8,16,24 : k-offset this thread stages
    int srcRow = min(rowBase + rr, N_NODES - 1);
    const float* xrow = x + (size_t)srcRow * K;
    int wrow = tid >> 3;          // 0..31 : W row this thread stages
    int wcol = (tid & 7) * 8;     // 0..56

    for (int kb = 0; kb < K; kb += 32) {
        __syncthreads();          // previous chunk fully consumed
        float4 a0 = *(const float4*)(xrow + kb + kk);
        float4 a1 = *(const float4*)(xrow + kb + kk + 4);
        float4 w0 = *(const float4*)(W + (size_t)(kb + wrow) * 64 + wcol);
        float4 w1 = *(const float4*)(W + (size_t)(kb + wrow) * 64 + wcol + 4);
        xT[kk + 0][rr] = a0.x; xT[kk + 1][rr] = a0.y;
        xT[kk + 2][rr] = a0.z; xT[kk + 3][rr] = a0.w;
        xT[kk + 4][rr] = a1.x; xT[kk + 5][rr] = a1.y;
        xT[kk + 6][rr] = a1.z; xT[kk + 7][rr] = a1.w;
        *(float4*)&Wc[wrow][wcol] = w0;
        *(float4*)&Wc[wrow][wcol + 4] = w1;
        __syncthreads();
#pragma unroll 8
        for (int k2 = 0; k2 < 32; ++k2) {
            float4 xa = *(const float4*)&xT[k2][ty2 * 4];
            float4 wb = *(const float4*)&Wc[k2][tx2 * 4];
            acc[0][0] = fmaf(xa.x, wb.x, acc[0][0]);
            acc[0][1] = fmaf(xa.x, wb.y, acc[0][1]);
            acc[0][2] = fmaf(xa.x, wb.z, acc[0][2]);
            acc[0][3] = fmaf(xa.x, wb.w, acc[0][3]);
            acc[1][0] = fmaf(xa.y, wb.x, acc[1][0]);
            acc[1][1] = fmaf(xa.y, wb.y, acc[1][1]);
            acc[1][2] = fmaf(xa.y, wb.z, acc[1][2]);
            acc[1][3] = fmaf(xa.y, wb.w, acc[1][3]);
            acc[2][0] = fmaf(xa.z, wb.x, acc[2][0]);
            acc[2][1] = fmaf(xa.z, wb.y, acc[2][1]);
            acc[2][2] = fmaf(xa.z, wb.z, acc[2][2]);
            acc[2][3] = fmaf(xa.z, wb.w, acc[2][3]);
            acc[3][0] = fmaf(xa.w, wb.x, acc[3][0]);
            acc[3][1] = fmaf(xa.w, wb.y, acc[3][1]);
            acc[3][2] = fmaf(xa.w, wb.z, acc[3][2]);
            acc[3][3] = fmaf(xa.w, wb.w, acc[3][3]);
        }
    }

    // epilogue: fp16 Wh store + per-row attention dots (f32)
    float4 as4 = *(const float4*)(aW + tx2 * 4);
    float4 at4 = *(const float4*)(aW + 64 + tx2 * 4);
#pragma unroll
    for (int r = 0; r < 4; ++r) {
        int row = rowBase + ty2 * 4 + r;
        if (row >= N_NODES) continue;
        H4 hv;
        hv.a = __floats2half2_rn(acc[r][0], acc[r][1]);
        hv.b = __floats2half2_rn(acc[r][2], acc[r][3]);
        WhH[(size_t)row * 16 + tx2] = hv;
        float ps = acc[r][0] * as4.x + acc[r][1] * as4.y + acc[r][2] * as4.z + acc[r][3] * as4.w;
        float pt = acc[r][0] * at4.x + acc[r][1] * at4.y + acc[r][2] * at4.z + acc[r][3] * at4.w;
#pragma unroll
        for (int o = 1; o < 16; o <<= 1) {
            ps += __shfl_xor(ps, o, 64);
            pt += __shfl_xor(pt, o, 64);
        }
        if (tx2 == 0) { alpha_s[row] = ps; alpha_t[row] = pt; }
    }
}

// ---- per-dst-node fused: attention softmax + scatter-max aggregation -------
template<int HEAD>
__global__ void k_node_aggr(const int* __restrict__ rowptr, const int* __restrict__ src_sorted,
                            const float* __restrict__ alpha_s, const float* __restrict__ alpha_t,
                            const float* __restrict__ ab, const H4* __restrict__ WhH,
                            const float* __restrict__ bias,
                            const float* __restrict__ Wo, const float* __restrict__ bo,
                            float* __restrict__ outp) {
    __shared__ float sWo[HEAD ? 64 * N_CLS : 1];
    __shared__ float sh[HEAD ? 4 * 64 : 1];
    __shared__ float2 pairs[4][64];
    int lane = threadIdx.x, w = threadIdx.y;
    if (HEAD) {
        int tid = w * 64 + lane;
        for (int i = tid; i < 64 * N_CLS; i += 256) sWo[i] = Wo[i];
    }
    int d = blockIdx.x * 4 + w;            // grid exact: 12500*4 == N_NODES
    int rs = rowptr[d], re = rowptr[d + 1];
    int deg = re - rs;
    float at = alpha_t[d] + ab[0];
    int g = lane >> 4, fl = lane & 15;

    float z;
    float4 vmax = make_float4(-INFINITY, -INFINITY, -INFINITY, -INFINITY);

    if (deg <= 64) {
        // --- single-chunk fast path ---
        int sv = src_sorted[rs + min(lane, deg - 1)];
        float t = alpha_s[sv] + at;
        t = t > 0.f ? t : 0.2f * t;
        float ev = __expf(t);                  // no max-subtract: |t| is O(1)
        float zz = (lane < deg) ? ev : 0.f;
#pragma unroll
        for (int o = 32; o; o >>= 1) zz += __shfl_xor(zz, o, 64);
        z = zz;
        pairs[w][lane] = make_float2(__int_as_float(sv), ev);
        for (int jb = 0; jb < deg; jb += 16) {
#pragma unroll
            for (int b = 0; b < 4; ++b) {
                if (jb + 4 * b < deg) {        // WAVE-UNIFORM: tail quads skipped
                    int j = jb + 4 * b + g;
                    j = j < deg ? j : deg - 1; // dup edges no-ops under max
                    float2 pe = pairs[w][j];   // uniform in group -> broadcast
                    int   sj = __float_as_int(pe.x);
                    float ej = pe.y;
                    H4 hv = WhH[(size_t)sj * 16 + fl];
                    float2 fa = __half22float2(hv.a);
                    float2 fb = __half22float2(hv.b);
                    vmax.x = fmaxf(vmax.x, ej * fa.x);
                    vmax.y = fmaxf(vmax.y, ej * fa.y);
                    vmax.z = fmaxf(vmax.z, ej * fb.x);
                    vmax.w = fmaxf(vmax.w, ej * fb.y);
                }
            }
        }
    } else {
        // --- rare slow path: chunked two-pass, scalar fp16 gather ---
        float m = -INFINITY;
        for (int base = rs; base < re; base += 64) {
            int idx = base + lane;
            float sim = -INFINITY;
            if (idx < re) {
                int sv = src_sorted[idx];
                float t = alpha_s[sv] + at;
                sim = t > 0.f ? t : 0.2f * t;
            }
#pragma unroll
            for (int o = 32; o; o >>= 1) sim = fmaxf(sim, __shfl_xor(sim, o, 64));
            m = fmaxf(m, sim);
        }
        z = 0.f;
        float vsc = -INFINITY;
        for (int base = rs; base < re; base += 64) {
            int idx = base + lane;
            int cnt = min(64, re - base);
            int svv = 0;
            float ev = 0.f;
            if (idx < re) {
                svv = src_sorted[idx];
                float t = alpha_s[svv] + at;
                t = t > 0.f ? t : 0.2f * t;
                ev = __expf(t - m);
            }
            float sz = ev;
#pragma unroll
            for (int o = 32; o; o >>= 1) sz += __shfl_xor(sz, o, 64);
            z += sz;
            for (int j = 0; j < cnt; ++j) {
                int sj = __shfl(svv, j, 64);
                float ej = __shfl(ev, j, 64);
                float v = __half2float(((const __half*)WhH)[(size_t)sj * 64 + lane]);
                vsc = fmaxf(vsc, ej * v);
            }
        }
        vmax.x = __shfl(vsc, 4 * fl + 0, 64);
        vmax.y = __shfl(vsc, 4 * fl + 1, 64);
        vmax.z = __shfl(vsc, 4 * fl + 2, 64);
        vmax.w = __shfl(vsc, 4 * fl + 3, 64);
    }

    // combine across the 4 lane groups (fast path partials; slow path idempotent)
#pragma unroll
    for (int o = 16; o <= 32; o <<= 1) {
        vmax.x = fmaxf(vmax.x, __shfl_xor(vmax.x, o, 64));
        vmax.y = fmaxf(vmax.y, __shfl_xor(vmax.y, o, 64));
        vmax.z = fmaxf(vmax.z, __shfl_xor(vmax.z, o, 64));
        vmax.w = fmaxf(vmax.w, __shfl_xor(vmax.w, o, 64));
    }
    // max(e_j/z * s_j) == max(e_j * s_j)/z since z > 0
    float4 bb = ((const float4*)bias)[fl];
    float4 h4;
    h4.x = fmaxf(vmax.x / z + bb.x, 0.f);
    h4.y = fmaxf(vmax.y / z + bb.y, 0.f);
    h4.z = fmaxf(vmax.z / z + bb.z, 0.f);
    h4.w = fmaxf(vmax.w / z + bb.w, 0.f);

    if (!HEAD) {
        if (g == 0) ((float4*)(outp + (size_t)d * 64))[fl] = h4;
    } else {
        if (g == 0) ((float4*)(sh + w * 64))[fl] = h4;
        __syncthreads();
        float logit = -INFINITY;
        if (lane < N_CLS) {
            float acc = bo[lane];
#pragma unroll
            for (int k = 0; k < 64; ++k) acc = fmaf(sh[w * 64 + k], sWo[k * N_CLS + lane], acc);
            logit = acc;
        }
        float mx = logit;
#pragma unroll
        for (int o = 32; o; o >>= 1) mx = fmaxf(mx, __shfl_xor(mx, o, 64));
        float ex = (lane < N_CLS) ? __expf(logit - mx) : 0.f;
        float sm = ex;
#pragma unroll
        for (int o = 32; o; o >>= 1) sm += __shfl_xor(sm, o, 64);
        float lse = mx + __logf(sm);
        if (lane < N_CLS) outp[(size_t)d * N_CLS + lane] = logit - lse;
    }
}

extern "C" void kernel_launch(void* const* d_in, const int* in_sizes, int n_in,
                              void* d_out, int out_size, void* d_ws, size_t ws_size,
                              hipStream_t stream) {
    const float* x   = (const float*)d_in[0];
    const void*  ei  = d_in[1];
    const float* W1  = (const float*)d_in[2];
    const float* aW1 = (const float*)d_in[3];
    const float* ab1 = (const float*)d_in[4];
    const float* b1  = (const float*)d_in[5];
    const float* W2  = (const float*)d_in[6];
    const float* aW2 = (const float*)d_in[7];
    const float* ab2 = (const float*)d_in[8];
    const float* b2  = (const float*)d_in[9];
    const float* Wo  = (const float*)d_in[10];
    const float* bo  = (const float*)d_in[11];
    float* out = (float*)d_out;

    char* ws = (char*)d_ws;
    size_t off = 0;
    auto alloc = [&](size_t bytes) {
        void* p = ws + off;
        off += (bytes + 255) & ~(size_t)255;
        return p;
    };
    int*   src32      = (int*)alloc((size_t)N_EDGES * 4);
    int*   dst32      = (int*)alloc((size_t)N_EDGES * 4);
    int*   deg        = (int*)alloc((size_t)N_NODES * 4);
    int*   rowptr     = (int*)alloc((size_t)(N_NODES + 1) * 4);
    int*   cursor     = (int*)alloc((size_t)N_NODES * 4);
    int*   partials   = (int*)alloc((size_t)SCAN_B * 4);
    int*   src_sorted = (int*)alloc((size_t)E_TOT * 4);
    H4*    WhH        = (H4*)alloc((size_t)N_NODES * 64 * 2);
    float* h_mid      = (float*)alloc((size_t)N_NODES * 64 * 4);
    float* alpha_s    = (float*)alloc((size_t)N_NODES * 4);
    float* alpha_t    = (float*)alloc((size_t)N_NODES * 4);

    const int B = 256;
    int gEdgeE = (N_EDGES + B - 1) / B;
    int gEdgeT = (E_TOT + B - 1) / B;
    dim3 blk2(64, 4);
    int gRow  = N_NODES / 4;            // 12500, exact
    int gGemm = (N_NODES + 63) / 64;    // 782

    // ---- CSR build
    hipMemsetAsync(deg, 0, (size_t)N_NODES * 4, stream);
    k_convert<<<gEdgeE, B, 0, stream>>>(ei, src32, dst32, deg);
    k_scan1<<<N_CHUNKS, SCAN_B, 0, stream>>>(deg, rowptr, partials);
    k_scan2<<<1, SCAN_B, 0, stream>>>(partials);
    k_scan3<<<N_CHUNKS, SCAN_B, 0, stream>>>(partials, rowptr, cursor);
    k_scatter_csr<<<gEdgeT, B, 0, stream>>>(src32, dst32, cursor, src_sorted);

    // ---- layer 1
    k_gemm_alpha<128><<<gGemm, 256, 0, stream>>>(x, W1, aW1, WhH, alpha_s, alpha_t);
    k_node_aggr<0><<<gRow, blk2, 0, stream>>>(rowptr, src_sorted, alpha_s, alpha_t,
                                              ab1, WhH, b1, nullptr, nullptr, h_mid);

    // ---- layer 2 (+ fused output head)
    k_gemm_alpha<64><<<gGemm, 256, 0, stream>>>(h_mid, W2, aW2, WhH, alpha_s, alpha_t);
    k_node_aggr<1><<<gRow, blk2, 0, stream>>>(rowptr, src_sorted, alpha_s, alpha_t,
                                              ab2, WhH, b2, Wo, bo, out);
}

// Round 8
// 214.567 us; speedup vs baseline: 3.0942x; 1.0296x over previous
//
#include <hip/hip_runtime.h>
#include <hip/hip_fp16.h>
#include <math.h>

#define N_NODES 50000
#define N_EDGES 800000
#define E_TOT   (N_EDGES + N_NODES)
#define D_HID   64
#define N_CLS   40
#define SCAN_B  256
#define N_CHUNKS ((N_NODES + SCAN_B - 1) / SCAN_B)   // 196

struct __align__(8) H4 { __half2 a, b; };   // 4 halves = 8 bytes

// ROCm 7.2 hip_fp16.h lacks __hmax2/__hmul2 — emit VOP3P packed ops directly.
__device__ __forceinline__ unsigned pk_max_f16(unsigned a, unsigned b) {
    unsigned r;
    asm("v_pk_max_f16 %0, %1, %2" : "=v"(r) : "v"(a), "v"(b));
    return r;
}
__device__ __forceinline__ unsigned pk_mul_f16(unsigned a, unsigned b) {
    unsigned r;
    asm("v_pk_mul_f16 %0, %1, %2" : "=v"(r) : "v"(a), "v"(b));
    return r;
}

// ---- convert (+ inline dtype detect, + degree histogram) -------------------
__global__ void k_convert(const void* ei, int* __restrict__ src32,
                          int* __restrict__ dst32, int* __restrict__ deg) {
    __shared__ int s_is32;
    if (threadIdx.x == 0) s_is32 = 0;
    __syncthreads();
    const int* p32 = (const int*)ei;
    if (p32[2 * threadIdx.x + 1] != 0) atomicOr(&s_is32, 1);
    __syncthreads();
    int e = blockIdx.x * 256 + threadIdx.x;
    if (e >= N_EDGES) return;
    int s, d;
    if (s_is32) {
        s = p32[e]; d = p32[N_EDGES + e];
    } else {
        const long long* p64 = (const long long*)ei;
        s = (int)p64[e]; d = (int)p64[N_EDGES + e];
    }
    src32[e] = s; dst32[e] = d;
    atomicAdd(&deg[d], 1);
}

// ---- CSR build: scan -> scatter --------------------------------------------
__device__ __forceinline__ int block_scan_incl(int v, int* wsum) {
    int lane = threadIdx.x & 63, w = threadIdx.x >> 6;
    int s = v;
#pragma unroll
    for (int d = 1; d < 64; d <<= 1) {
        int t = __shfl_up(s, d, 64);
        if (lane >= d) s += t;
    }
    if (lane == 63) wsum[w] = s;
    __syncthreads();
    int add = 0;
    for (int ww = 0; ww < (threadIdx.x >> 6); ++ww) add += wsum[ww];
    return s + add;
}

__global__ void k_scan1(const int* __restrict__ deg, int* __restrict__ rowptr,
                        int* __restrict__ partials) {
    __shared__ int wsum[4];
    int i = blockIdx.x * SCAN_B + threadIdx.x;
    int v = (i < N_NODES) ? deg[i] + 1 : 0;      // +1 = self loop
    int s = block_scan_incl(v, wsum);
    if (i < N_NODES) rowptr[i] = s - v;          // block-local exclusive
    if (threadIdx.x == SCAN_B - 1) partials[blockIdx.x] = s;
}

__global__ void k_scan2(int* partials) {
    __shared__ int wsum[4];
    int i = threadIdx.x;
    int v = (i < N_CHUNKS) ? partials[i] : 0;
    int s = block_scan_incl(v, wsum);
    if (i < N_CHUNKS) partials[i] = s - v;       // exclusive
}

__global__ void k_scan3(const int* __restrict__ partials, int* __restrict__ rowptr,
                        int* __restrict__ cursor) {
    int i = blockIdx.x * SCAN_B + threadIdx.x;
    if (i < N_NODES) {
        int r = rowptr[i] + partials[blockIdx.x];
        rowptr[i] = r;
        cursor[i] = r;
    }
    if (blockIdx.x == 0 && threadIdx.x == 0) rowptr[N_NODES] = E_TOT;
}

__global__ void k_scatter_csr(const int* __restrict__ src32, const int* __restrict__ dst32,
                              int* __restrict__ cursor, int* __restrict__ src_sorted) {
    int e = blockIdx.x * blockDim.x + threadIdx.x;
    if (e >= E_TOT) return;
    int s, d;
    if (e < N_EDGES) { s = src32[e]; d = dst32[e]; } else { s = d = e - N_EDGES; }
    int pos = atomicAdd(&cursor[d], 1);
    src_sorted[pos] = s;
}

// ---- register-tiled GEMM: WhH(fp16) = x@W (+ alpha_s/alpha_t dots) ---------
template<int K>
__global__ __launch_bounds__(256, 4) void k_gemm_alpha(
        const float* __restrict__ x, const float* __restrict__ W,
        const float* __restrict__ aW,
        H4* __restrict__ WhH,
        float* __restrict__ alpha_s, float* __restrict__ alpha_t) {
    __shared__ float Wc[32][68];
    __shared__ float xT[32][68];
    int tid = threadIdx.x;
    int tx2 = tid & 15, ty2 = tid >> 4;
    int rowBase = blockIdx.x * 64;

    float acc[4][4];
#pragma unroll
    for (int r = 0; r < 4; ++r)
#pragma unroll
        for (int c = 0; c < 4; ++c) acc[r][c] = 0.f;

    int rr = tid >> 2;            // 0..63 : x row this thread stages
    int kk = (tid & 3) * 8;       // 0,8,16,24 : k-offset this thread stages
    int srcRow = min(rowBase + rr, N_NODES - 1);
    const float* xrow = x + (size_t)srcRow * K;
    int wrow = tid >> 3;          // 0..31 : W row this thread stages
    int wcol = (tid & 7) * 8;     // 0..56

    for (int kb = 0; kb < K; kb += 32) {
        __syncthreads();          // previous chunk fully consumed
        float4 a0 = *(const float4*)(xrow + kb + kk);
        float4 a1 = *(const float4*)(xrow + kb + kk + 4);
        float4 w0 = *(const float4*)(W + (size_t)(kb + wrow) * 64 + wcol);
        float4 w1 = *(const float4*)(W + (size_t)(kb + wrow) * 64 + wcol + 4);
        xT[kk + 0][rr] = a0.x; xT[kk + 1][rr] = a0.y;
        xT[kk + 2][rr] = a0.z; xT[kk + 3][rr] = a0.w;
        xT[kk + 4][rr] = a1.x; xT[kk + 5][rr] = a1.y;
        xT[kk + 6][rr] = a1.z; xT[kk + 7][rr] = a1.w;
        *(float4*)&Wc[wrow][wcol] = w0;
        *(float4*)&Wc[wrow][wcol + 4] = w1;
        __syncthreads();
#pragma unroll 8
        for (int k2 = 0; k2 < 32; ++k2) {
            float4 xa = *(const float4*)&xT[k2][ty2 * 4];
            float4 wb = *(const float4*)&Wc[k2][tx2 * 4];
            acc[0][0] = fmaf(xa.x, wb.x, acc[0][0]);
            acc[0][1] = fmaf(xa.x, wb.y, acc[0][1]);
            acc[0][2] = fmaf(xa.x, wb.z, acc[0][2]);
            acc[0][3] = fmaf(xa.x, wb.w, acc[0][3]);
            acc[1][0] = fmaf(xa.y, wb.x, acc[1][0]);
            acc[1][1] = fmaf(xa.y, wb.y, acc[1][1]);
            acc[1][2] = fmaf(xa.y, wb.z, acc[1][2]);
            acc[1][3] = fmaf(xa.y, wb.w, acc[1][3]);
            acc[2][0] = fmaf(xa.z, wb.x, acc[2][0]);
            acc[2][1] = fmaf(xa.z, wb.y, acc[2][1]);
            acc[2][2] = fmaf(xa.z, wb.z, acc[2][2]);
            acc[2][3] = fmaf(xa.z, wb.w, acc[2][3]);
            acc[3][0] = fmaf(xa.w, wb.x, acc[3][0]);
            acc[3][1] = fmaf(xa.w, wb.y, acc[3][1]);
            acc[3][2] = fmaf(xa.w, wb.z, acc[3][2]);
            acc[3][3] = fmaf(xa.w, wb.w, acc[3][3]);
        }
    }

    // epilogue: fp16 Wh store + per-row attention dots (f32)
    float4 as4 = *(const float4*)(aW + tx2 * 4);
    float4 at4 = *(const float4*)(aW + 64 + tx2 * 4);
#pragma unroll
    for (int r = 0; r < 4; ++r) {
        int row = rowBase + ty2 * 4 + r;
        if (row >= N_NODES) continue;
        H4 hv;
        hv.a = __floats2half2_rn(acc[r][0], acc[r][1]);
        hv.b = __floats2half2_rn(acc[r][2], acc[r][3]);
        WhH[(size_t)row * 16 + tx2] = hv;
        float ps = acc[r][0] * as4.x + acc[r][1] * as4.y + acc[r][2] * as4.z + acc[r][3] * as4.w;
        float pt = acc[r][0] * at4.x + acc[r][1] * at4.y + acc[r][2] * at4.z + acc[r][3] * at4.w;
#pragma unroll
        for (int o = 1; o < 16; o <<= 1) {
            ps += __shfl_xor(ps, o, 64);
            pt += __shfl_xor(pt, o, 64);
        }
        if (tx2 == 0) { alpha_s[row] = ps; alpha_t[row] = pt; }
    }
}

// ---- per-dst-node fused: attention softmax + scatter-max aggregation -------
// One wave per node. Fast path: 8-lane groups (g2=lane>>3), lane loads 16B
// (8 halves) of the 128B fp16 row -> 8 edges per round; packed v_pk_mul_f16/
// v_pk_max_f16 accumulate; ev + row-offset distributed via shfl (no LDS).
// Wave-uniform round tiers at deg>16 / deg>32; clamped dups no-ops under max.
__device__ __forceinline__ unsigned pkmax_xor(unsigned v, int o) {
    unsigned t = __shfl_xor((int)v, o, 64);
    return pk_max_f16(v, t);
}

template<int HEAD>
__global__ void k_node_aggr(const int* __restrict__ rowptr, const int* __restrict__ src_sorted,
                            const float* __restrict__ alpha_s, const float* __restrict__ alpha_t,
                            const float* __restrict__ ab, const H4* __restrict__ WhH,
                            const float* __restrict__ bias,
                            const float* __restrict__ Wo, const float* __restrict__ bo,
                            float* __restrict__ outp) {
    __shared__ float sWo[HEAD ? 64 * N_CLS : 1];
    __shared__ float sh[HEAD ? 4 * 64 : 1];
    int lane = threadIdx.x, w = threadIdx.y;
    if (HEAD) {
        int tid = w * 64 + lane;
        for (int i = tid; i < 64 * N_CLS; i += 256) sWo[i] = Wo[i];
    }
    int d = blockIdx.x * 4 + w;            // grid exact: 12500*4 == N_NODES
    int rs = rowptr[d], re = rowptr[d + 1];
    int deg = re - rs;
    float at = alpha_t[d] + ab[0];
    int g2 = lane >> 3, fl2 = lane & 7;
    const char* whb = (const char*)WhH;

    float z;
    float vm8[8];

    if (deg <= 64) {
        // --- fast path ---
        int sv = src_sorted[rs + min(lane, deg - 1)];
        float t = alpha_s[sv] + at;
        t = t > 0.f ? t : 0.2f * t;
        float ev = __expf(t);                  // no max-subtract: |t| is O(1)
        float zz = (lane < deg) ? ev : 0.f;
#pragma unroll
        for (int o = 32; o; o >>= 1) zz += __shfl_xor(zz, o, 64);
        z = zz;
        int ofs = sv * 128;                    // byte offset of fp16 row

        unsigned NEGINF2 = 0xFC00FC00u;        // {-inf, -inf} fp16
        unsigned vm0 = NEGINF2, vm1 = NEGINF2, vm2 = NEGINF2, vm3 = NEGINF2;
#define ROUND(r) { \
        int j = (r) * 8 + g2; j = j < deg ? j : deg - 1;                  \
        float ej = __shfl(ev, j, 64);                                     \
        int ro = __shfl(ofs, j, 64);                                      \
        uint4 hv = *(const uint4*)(whb + ro + fl2 * 16);                  \
        __half2 ejh = __float2half2_rn(ej);                               \
        unsigned ej2 = *(unsigned*)&ejh;                                  \
        vm0 = pk_max_f16(vm0, pk_mul_f16(ej2, hv.x));                     \
        vm1 = pk_max_f16(vm1, pk_mul_f16(ej2, hv.y));                     \
        vm2 = pk_max_f16(vm2, pk_mul_f16(ej2, hv.z));                     \
        vm3 = pk_max_f16(vm3, pk_mul_f16(ej2, hv.w)); }

        ROUND(0) ROUND(1)
        if (deg > 16) {
            ROUND(2) ROUND(3)
            if (deg > 32) { ROUND(4) ROUND(5) ROUND(6) ROUND(7) }
        }
#undef ROUND
        // combine across the 8 groups (lane bits 3,4,5) in packed fp16
#pragma unroll
        for (int o = 8; o <= 32; o <<= 1) {
            vm0 = pkmax_xor(vm0, o); vm1 = pkmax_xor(vm1, o);
            vm2 = pkmax_xor(vm2, o); vm3 = pkmax_xor(vm3, o);
        }
        float2 f0 = __half22float2(*(__half2*)&vm0), f1 = __half22float2(*(__half2*)&vm1);
        float2 f2 = __half22float2(*(__half2*)&vm2), f3 = __half22float2(*(__half2*)&vm3);
        vm8[0] = f0.x; vm8[1] = f0.y; vm8[2] = f1.x; vm8[3] = f1.y;
        vm8[4] = f2.x; vm8[5] = f2.y; vm8[6] = f3.x; vm8[7] = f3.y;
    } else {
        // --- rare slow path: chunked two-pass, scalar fp16 gather ---
        float m = -INFINITY;
        for (int base = rs; base < re; base += 64) {
            int idx = base + lane;
            float sim = -INFINITY;
            if (idx < re) {
                int sv = src_sorted[idx];
                float t = alpha_s[sv] + at;
                sim = t > 0.f ? t : 0.2f * t;
            }
#pragma unroll
            for (int o = 32; o; o >>= 1) sim = fmaxf(sim, __shfl_xor(sim, o, 64));
            m = fmaxf(m, sim);
        }
        z = 0.f;
        float vsc = -INFINITY;
        for (int base = rs; base < re; base += 64) {
            int idx = base + lane;
            int cnt = min(64, re - base);
            int svv = 0;
            float ev = 0.f;
            if (idx < re) {
                svv = src_sorted[idx];
                float t = alpha_s[svv] + at;
                t = t > 0.f ? t : 0.2f * t;
                ev = __expf(t - m);
            }
            float sz = ev;
#pragma unroll
            for (int o = 32; o; o >>= 1) sz += __shfl_xor(sz, o, 64);
            z += sz;
            for (int j = 0; j < cnt; ++j) {
                int sj = __shfl(svv, j, 64);
                float ej = __shfl(ev, j, 64);
                float v = __half2float(((const __half*)WhH)[(size_t)sj * 64 + lane]);
                vsc = fmaxf(vsc, ej * v);
            }
        }
        // redistribute: this lane needs features fl2*8 .. fl2*8+7
#pragma unroll
        for (int q = 0; q < 8; ++q) vm8[q] = __shfl(vsc, fl2 * 8 + q, 64);
    }

    // unified epilogue: h = vmax/z + bias, relu. Lane column fl2 owns feats
    // fl2*8..+7; lanes with g2==0 store.
    float rz = 1.0f / z;
    float4 b0 = *(const float4*)(bias + fl2 * 8);
    float4 b1 = *(const float4*)(bias + fl2 * 8 + 4);
    float h8[8];
    h8[0] = fmaxf(vm8[0] * rz + b0.x, 0.f);
    h8[1] = fmaxf(vm8[1] * rz + b0.y, 0.f);
    h8[2] = fmaxf(vm8[2] * rz + b0.z, 0.f);
    h8[3] = fmaxf(vm8[3] * rz + b0.w, 0.f);
    h8[4] = fmaxf(vm8[4] * rz + b1.x, 0.f);
    h8[5] = fmaxf(vm8[5] * rz + b1.y, 0.f);
    h8[6] = fmaxf(vm8[6] * rz + b1.z, 0.f);
    h8[7] = fmaxf(vm8[7] * rz + b1.w, 0.f);

    if (!HEAD) {
        if (g2 == 0) {
            float* op = outp + (size_t)d * 64 + fl2 * 8;
            *(float4*)op = make_float4(h8[0], h8[1], h8[2], h8[3]);
            *(float4*)(op + 4) = make_float4(h8[4], h8[5], h8[6], h8[7]);
        }
    } else {
        if (g2 == 0) {
            float* sp = sh + w * 64 + fl2 * 8;
            *(float4*)sp = make_float4(h8[0], h8[1], h8[2], h8[3]);
            *(float4*)(sp + 4) = make_float4(h8[4], h8[5], h8[6], h8[7]);
        }
        __syncthreads();
        float logit = -INFINITY;
        if (lane < N_CLS) {
            float acc = bo[lane];
#pragma unroll
            for (int k = 0; k < 64; ++k) acc = fmaf(sh[w * 64 + k], sWo[k * N_CLS + lane], acc);
            logit = acc;
        }
        float mx = logit;
#pragma unroll
        for (int o = 32; o; o >>= 1) mx = fmaxf(mx, __shfl_xor(mx, o, 64));
        float ex = (lane < N_CLS) ? __expf(logit - mx) : 0.f;
        float sm = ex;
#pragma unroll
        for (int o = 32; o; o >>= 1) sm += __shfl_xor(sm, o, 64);
        float lse = mx + __logf(sm);
        if (lane < N_CLS) outp[(size_t)d * N_CLS + lane] = logit - lse;
    }
}

extern "C" void kernel_launch(void* const* d_in, const int* in_sizes, int n_in,
                              void* d_out, int out_size, void* d_ws, size_t ws_size,
                              hipStream_t stream) {
    const float* x   = (const float*)d_in[0];
    const void*  ei  = d_in[1];
    const float* W1  = (const float*)d_in[2];
    const float* aW1 = (const float*)d_in[3];
    const float* ab1 = (const float*)d_in[4];
    const float* b1  = (const float*)d_in[5];
    const float* W2  = (const float*)d_in[6];
    const float* aW2 = (const float*)d_in[7];
    const float* ab2 = (const float*)d_in[8];
    const float* b2  = (const float*)d_in[9];
    const float* Wo  = (const float*)d_in[10];
    const float* bo  = (const float*)d_in[11];
    float* out = (float*)d_out;

    char* ws = (char*)d_ws;
    size_t off = 0;
    auto alloc = [&](size_t bytes) {
        void* p = ws + off;
        off += (bytes + 255) & ~(size_t)255;
        return p;
    };
    int*   src32      = (int*)alloc((size_t)N_EDGES * 4);
    int*   dst32      = (int*)alloc((size_t)N_EDGES * 4);
    int*   deg        = (int*)alloc((size_t)N_NODES * 4);
    int*   rowptr     = (int*)alloc((size_t)(N_NODES + 1) * 4);
    int*   cursor     = (int*)alloc((size_t)N_NODES * 4);
    int*   partials   = (int*)alloc((size_t)SCAN_B * 4);
    int*   src_sorted = (int*)alloc((size_t)E_TOT * 4);
    H4*    WhH        = (H4*)alloc((size_t)N_NODES * 64 * 2);
    float* h_mid      = (float*)alloc((size_t)N_NODES * 64 * 4);
    float* alpha_s    = (float*)alloc((size_t)N_NODES * 4);
    float* alpha_t    = (float*)alloc((size_t)N_NODES * 4);

    const int B = 256;
    int gEdgeE = (N_EDGES + B - 1) / B;
    int gEdgeT = (E_TOT + B - 1) / B;
    dim3 blk2(64, 4);
    int gRow  = N_NODES / 4;            // 12500, exact
    int gGemm = (N_NODES + 63) / 64;    // 782

    // ---- CSR build
    hipMemsetAsync(deg, 0, (size_t)N_NODES * 4, stream);
    k_convert<<<gEdgeE, B, 0, stream>>>(ei, src32, dst32, deg);
    k_scan1<<<N_CHUNKS, SCAN_B, 0, stream>>>(deg, rowptr, partials);
    k_scan2<<<1, SCAN_B, 0, stream>>>(partials);
    k_scan3<<<N_CHUNKS, SCAN_B, 0, stream>>>(partials, rowptr, cursor);
    k_scatter_csr<<<gEdgeT, B, 0, stream>>>(src32, dst32, cursor, src_sorted);

    // ---- layer 1
    k_gemm_alpha<128><<<gGemm, 256, 0, stream>>>(x, W1, aW1, WhH, alpha_s, alpha_t);
    k_node_aggr<0><<<gRow, blk2, 0, stream>>>(rowptr, src_sorted, alpha_s, alpha_t,
                                              ab1, WhH, b1, nullptr, nullptr, h_mid);

    // ---- layer 2 (+ fused output head)
    k_gemm_alpha<64><<<gGemm, 256, 0, stream>>>(h_mid, W2, aW2, WhH, alpha_s, alpha_t);
    k_node_aggr<1><<<gRow, blk2, 0, stream>>>(rowptr, src_sorted, alpha_s, alpha_t,
                                              ab2, WhH, b2, Wo, bo, out);
}

// Round 9
// 205.894 us; speedup vs baseline: 3.2245x; 1.0421x over previous
//
#include <hip/hip_runtime.h>
#include <hip/hip_fp16.h>
#include <math.h>

#define N_NODES 50000
#define N_EDGES 800000
#define E_TOT   (N_EDGES + N_NODES)
#define D_HID   64
#define N_CLS   40
#define SCAN_B  256
#define N_CHUNKS ((N_NODES + SCAN_B - 1) / SCAN_B)   // 196

struct __align__(8) H4 { __half2 a, b; };   // 4 halves = 8 bytes

// ROCm 7.2 hip_fp16.h lacks __hmax2/__hmul2 — emit VOP3P packed ops directly.
__device__ __forceinline__ unsigned pk_max_f16(unsigned a, unsigned b) {
    unsigned r;
    asm("v_pk_max_f16 %0, %1, %2" : "=v"(r) : "v"(a), "v"(b));
    return r;
}
__device__ __forceinline__ unsigned pk_mul_f16(unsigned a, unsigned b) {
    unsigned r;
    asm("v_pk_mul_f16 %0, %1, %2" : "=v"(r) : "v"(a), "v"(b));
    return r;
}
__device__ __forceinline__ unsigned pkmax_xor(unsigned v, int o) {
    unsigned t = __shfl_xor((int)v, o, 64);
    return pk_max_f16(v, t);
}

// ---- convert (+ inline dtype detect, + degree histogram) -------------------
__global__ void k_convert(const void* ei, int* __restrict__ src32,
                          int* __restrict__ dst32, int* __restrict__ deg) {
    __shared__ int s_is32;
    if (threadIdx.x == 0) s_is32 = 0;
    __syncthreads();
    const int* p32 = (const int*)ei;
    if (p32[2 * threadIdx.x + 1] != 0) atomicOr(&s_is32, 1);
    __syncthreads();
    int e = blockIdx.x * 256 + threadIdx.x;
    if (e >= N_EDGES) return;
    int s, d;
    if (s_is32) {
        s = p32[e]; d = p32[N_EDGES + e];
    } else {
        const long long* p64 = (const long long*)ei;
        s = (int)p64[e]; d = (int)p64[N_EDGES + e];
    }
    src32[e] = s; dst32[e] = d;
    atomicAdd(&deg[d], 1);
}

// ---- CSR build: scan -> scatter --------------------------------------------
__device__ __forceinline__ int block_scan_incl(int v, int* wsum) {
    int lane = threadIdx.x & 63, w = threadIdx.x >> 6;
    int s = v;
#pragma unroll
    for (int d = 1; d < 64; d <<= 1) {
        int t = __shfl_up(s, d, 64);
        if (lane >= d) s += t;
    }
    if (lane == 63) wsum[w] = s;
    __syncthreads();
    int add = 0;
    for (int ww = 0; ww < (threadIdx.x >> 6); ++ww) add += wsum[ww];
    return s + add;
}

__global__ void k_scan1(const int* __restrict__ deg, int* __restrict__ rowptr,
                        int* __restrict__ partials) {
    __shared__ int wsum[4];
    int i = blockIdx.x * SCAN_B + threadIdx.x;
    int v = (i < N_NODES) ? deg[i] + 1 : 0;      // +1 = self loop
    int s = block_scan_incl(v, wsum);
    if (i < N_NODES) rowptr[i] = s - v;          // block-local exclusive
    if (threadIdx.x == SCAN_B - 1) partials[blockIdx.x] = s;
}

__global__ void k_scan2(int* partials) {
    __shared__ int wsum[4];
    int i = threadIdx.x;
    int v = (i < N_CHUNKS) ? partials[i] : 0;
    int s = block_scan_incl(v, wsum);
    if (i < N_CHUNKS) partials[i] = s - v;       // exclusive
}

__global__ void k_scan3(const int* __restrict__ partials, int* __restrict__ rowptr,
                        int* __restrict__ cursor) {
    int i = blockIdx.x * SCAN_B + threadIdx.x;
    if (i < N_NODES) {
        int r = rowptr[i] + partials[blockIdx.x];
        rowptr[i] = r;
        cursor[i] = r;
    }
    if (blockIdx.x == 0 && threadIdx.x == 0) rowptr[N_NODES] = E_TOT;
}

__global__ void k_scatter_csr(const int* __restrict__ src32, const int* __restrict__ dst32,
                              int* __restrict__ cursor, int* __restrict__ src_sorted) {
    int e = blockIdx.x * blockDim.x + threadIdx.x;
    if (e >= E_TOT) return;
    int s, d;
    if (e < N_EDGES) { s = src32[e]; d = dst32[e]; } else { s = d = e - N_EDGES; }
    int pos = atomicAdd(&cursor[d], 1);
    src_sorted[pos] = s;
}

// ---- register-tiled GEMM: WhH(fp16) = x@W (+ alpha_s/alpha_t dots) ---------
template<int K>
__global__ __launch_bounds__(256, 4) void k_gemm_alpha(
        const float* __restrict__ x, const float* __restrict__ W,
        const float* __restrict__ aW,
        H4* __restrict__ WhH,
        float* __restrict__ alpha_s, float* __restrict__ alpha_t) {
    __shared__ float Wc[32][68];
    __shared__ float xT[32][68];
    int tid = threadIdx.x;
    int tx2 = tid & 15, ty2 = tid >> 4;
    int rowBase = blockIdx.x * 64;

    float acc[4][4];
#pragma unroll
    for (int r = 0; r < 4; ++r)
#pragma unroll
        for (int c = 0; c < 4; ++c) acc[r][c] = 0.f;

    int rr = tid >> 2;            // 0..63 : x row this thread stages
    int kk = (tid & 3) * 8;       // 0,8,16,24 : k-offset this thread stages
    int srcRow = min(rowBase + rr, N_NODES - 1);
    const float* xrow = x + (size_t)srcRow * K;
    int wrow = tid >> 3;          // 0..31 : W row this thread stages
    int wcol = (tid & 7) * 8;     // 0..56

    for (int kb = 0; kb < K; kb += 32) {
        __syncthreads();          // previous chunk fully consumed
        float4 a0 = *(const float4*)(xrow + kb + kk);
        float4 a1 = *(const float4*)(xrow + kb + kk + 4);
        float4 w0 = *(const float4*)(W + (size_t)(kb + wrow) * 64 + wcol);
        float4 w1 = *(const float4*)(W + (size_t)(kb + wrow) * 64 + wcol + 4);
        xT[kk + 0][rr] = a0.x; xT[kk + 1][rr] = a0.y;
        xT[kk + 2][rr] = a0.z; xT[kk + 3][rr] = a0.w;
        xT[kk + 4][rr] = a1.x; xT[kk + 5][rr] = a1.y;
        xT[kk + 6][rr] = a1.z; xT[kk + 7][rr] = a1.w;
        *(float4*)&Wc[wrow][wcol] = w0;
        *(float4*)&Wc[wrow][wcol + 4] = w1;
        __syncthreads();
#pragma unroll 8
        for (int k2 = 0; k2 < 32; ++k2) {
            float4 xa = *(const float4*)&xT[k2][ty2 * 4];
            float4 wb = *(const float4*)&Wc[k2][tx2 * 4];
            acc[0][0] = fmaf(xa.x, wb.x, acc[0][0]);
            acc[0][1] = fmaf(xa.x, wb.y, acc[0][1]);
            acc[0][2] = fmaf(xa.x, wb.z, acc[0][2]);
            acc[0][3] = fmaf(xa.x, wb.w, acc[0][3]);
            acc[1][0] = fmaf(xa.y, wb.x, acc[1][0]);
            acc[1][1] = fmaf(xa.y, wb.y, acc[1][1]);
            acc[1][2] = fmaf(xa.y, wb.z, acc[1][2]);
            acc[1][3] = fmaf(xa.y, wb.w, acc[1][3]);
            acc[2][0] = fmaf(xa.z, wb.x, acc[2][0]);
            acc[2][1] = fmaf(xa.z, wb.y, acc[2][1]);
            acc[2][2] = fmaf(xa.z, wb.z, acc[2][2]);
            acc[2][3] = fmaf(xa.z, wb.w, acc[2][3]);
            acc[3][0] = fmaf(xa.w, wb.x, acc[3][0]);
            acc[3][1] = fmaf(xa.w, wb.y, acc[3][1]);
            acc[3][2] = fmaf(xa.w, wb.z, acc[3][2]);
            acc[3][3] = fmaf(xa.w, wb.w, acc[3][3]);
        }
    }

    // epilogue: fp16 Wh store + per-row attention dots (f32)
    float4 as4 = *(const float4*)(aW + tx2 * 4);
    float4 at4 = *(const float4*)(aW + 64 + tx2 * 4);
#pragma unroll
    for (int r = 0; r < 4; ++r) {
        int row = rowBase + ty2 * 4 + r;
        if (row >= N_NODES) continue;
        H4 hv;
        hv.a = __floats2half2_rn(acc[r][0], acc[r][1]);
        hv.b = __floats2half2_rn(acc[r][2], acc[r][3]);
        WhH[(size_t)row * 16 + tx2] = hv;
        float ps = acc[r][0] * as4.x + acc[r][1] * as4.y + acc[r][2] * as4.z + acc[r][3] * as4.w;
        float pt = acc[r][0] * at4.x + acc[r][1] * at4.y + acc[r][2] * at4.z + acc[r][3] * at4.w;
#pragma unroll
        for (int o = 1; o < 16; o <<= 1) {
            ps += __shfl_xor(ps, o, 64);
            pt += __shfl_xor(pt, o, 64);
        }
        if (tx2 == 0) { alpha_s[row] = ps; alpha_t[row] = pt; }
    }
}

// ---- slow path helper (deg > 64): chunked two-pass, scalar fp16 gather -----
__device__ void slow_node(int rs, int re, const int* __restrict__ src_sorted,
                          const float* __restrict__ alpha_s, float at,
                          const H4* __restrict__ WhH, int lane, int fl2,
                          float& z, unsigned vm[4]) {
    float m = -INFINITY;
    for (int base = rs; base < re; base += 64) {
        int idx = base + lane;
        float sim = -INFINITY;
        if (idx < re) {
            int sv = src_sorted[idx];
            float t = alpha_s[sv] + at;
            sim = t > 0.f ? t : 0.2f * t;
        }
#pragma unroll
        for (int o = 32; o; o >>= 1) sim = fmaxf(sim, __shfl_xor(sim, o, 64));
        m = fmaxf(m, sim);
    }
    z = 0.f;
    float vsc = -INFINITY;
    for (int base = rs; base < re; base += 64) {
        int idx = base + lane;
        int cnt = min(64, re - base);
        int svv = 0;
        float ev = 0.f;
        if (idx < re) {
            svv = src_sorted[idx];
            float t = alpha_s[svv] + at;
            t = t > 0.f ? t : 0.2f * t;
            ev = __expf(t - m);
        }
        float sz = ev;
#pragma unroll
        for (int o = 32; o; o >>= 1) sz += __shfl_xor(sz, o, 64);
        z += sz;
        for (int j = 0; j < cnt; ++j) {
            int sj = __shfl(svv, j, 64);
            float ej = __shfl(ev, j, 64);
            float v = __half2float(((const __half*)WhH)[(size_t)sj * 64 + lane]);
            vsc = fmaxf(vsc, ej * v);
        }
    }
    // pack: this lane's group column fl2 owns feats fl2*8 .. +7
#pragma unroll
    for (int q = 0; q < 4; ++q) {
        float a0 = __shfl(vsc, fl2 * 8 + 2 * q, 64);
        float a1 = __shfl(vsc, fl2 * 8 + 2 * q + 1, 64);
        __half2 p = __floats2half2_rn(a0, a1);
        vm[q] = *(unsigned*)&p;
    }
}

// ---- per-dst-node fused: attention softmax + scatter-max aggregation -------
// TWO nodes per wave (A,B): doubles outstanding misses & hides the dependent
// shfl-reduce chains of one node under the other's gather loads. Fast path:
// 8-lane groups, 16B/lane loads (8 edges/round/node), packed fp16 mul/max.
template<int HEAD>
__global__ void k_node_aggr(const int* __restrict__ rowptr, const int* __restrict__ src_sorted,
                            const float* __restrict__ alpha_s, const float* __restrict__ alpha_t,
                            const float* __restrict__ ab, const H4* __restrict__ WhH,
                            const float* __restrict__ bias,
                            const float* __restrict__ Wo, const float* __restrict__ bo,
                            float* __restrict__ outp) {
    __shared__ float sWo[HEAD ? 64 * N_CLS : 1];
    __shared__ float sh[HEAD ? 8 * 64 : 1];
    int lane = threadIdx.x, w = threadIdx.y;
    if (HEAD) {
        int tid = w * 64 + lane;
        for (int i = tid; i < 64 * N_CLS; i += 256) sWo[i] = Wo[i];
    }
    int dA = blockIdx.x * 8 + w * 2;       // grid exact: 6250*8 == N_NODES
    int dB = dA + 1;
    int rsA = rowptr[dA], reA = rowptr[dA + 1];
    int rsB = rowptr[dB], reB = rowptr[dB + 1];
    int degA = reA - rsA, degB = reB - rsB;
    float abv = ab[0];
    float atA = alpha_t[dA] + abv;
    float atB = alpha_t[dB] + abv;
    int g2 = lane >> 3, fl2 = lane & 7;
    const char* whb = (const char*)WhH;

    float zA, zB;
    unsigned vmA[4], vmB[4];

    if (degA <= 64 && degB <= 64) {
        // --- dual fast path ---
        int svA = src_sorted[rsA + min(lane, degA - 1)];
        int svB = src_sorted[rsB + min(lane, degB - 1)];
        float tA = alpha_s[svA] + atA; tA = tA > 0.f ? tA : 0.2f * tA;
        float tB = alpha_s[svB] + atB; tB = tB > 0.f ? tB : 0.2f * tB;
        float evA = __expf(tA);            // no max-subtract: |t| is O(1)
        float evB = __expf(tB);
        float zzA = (lane < degA) ? evA : 0.f;
        float zzB = (lane < degB) ? evB : 0.f;
#pragma unroll
        for (int o = 32; o; o >>= 1) {
            zzA += __shfl_xor(zzA, o, 64);
            zzB += __shfl_xor(zzB, o, 64);
        }
        zA = zzA; zB = zzB;
        int ofsA = svA * 128, ofsB = svB * 128;   // byte offsets of fp16 rows

        const unsigned NEGINF2 = 0xFC00FC00u;     // {-inf,-inf} fp16
        unsigned vA0 = NEGINF2, vA1 = NEGINF2, vA2 = NEGINF2, vA3 = NEGINF2;
        unsigned vB0 = NEGINF2, vB1 = NEGINF2, vB2 = NEGINF2, vB3 = NEGINF2;
#define ROUND(ev, ofs, deg, v0, v1, v2, v3, r) { \
        int j = (r) * 8 + g2; j = j < (deg) ? j : (deg) - 1;              \
        float ej = __shfl((ev), j, 64);                                   \
        int ro = __shfl((ofs), j, 64);                                    \
        uint4 hv = *(const uint4*)(whb + ro + fl2 * 16);                  \
        __half2 ejh = __float2half2_rn(ej);                               \
        unsigned ej2 = *(unsigned*)&ejh;                                  \
        v0 = pk_max_f16(v0, pk_mul_f16(ej2, hv.x));                       \
        v1 = pk_max_f16(v1, pk_mul_f16(ej2, hv.y));                       \
        v2 = pk_max_f16(v2, pk_mul_f16(ej2, hv.z));                       \
        v3 = pk_max_f16(v3, pk_mul_f16(ej2, hv.w)); }
#define RA(r) ROUND(evA, ofsA, degA, vA0, vA1, vA2, vA3, r)
#define RB(r) ROUND(evB, ofsB, degB, vB0, vB1, vB2, vB3, r)

        RA(0) RB(0) RA(1) RB(1)
        if (degA > 16) { RA(2) RA(3) }
        if (degB > 16) { RB(2) RB(3) }
        if (degA > 32) { RA(4) RA(5) RA(6) RA(7) }
        if (degB > 32) { RB(4) RB(5) RB(6) RB(7) }
#undef RA
#undef RB
#undef ROUND
        // combine across the 8 groups (lane bits 3,4,5) in packed fp16
#pragma unroll
        for (int o = 8; o <= 32; o <<= 1) {
            vA0 = pkmax_xor(vA0, o); vA1 = pkmax_xor(vA1, o);
            vA2 = pkmax_xor(vA2, o); vA3 = pkmax_xor(vA3, o);
            vB0 = pkmax_xor(vB0, o); vB1 = pkmax_xor(vB1, o);
            vB2 = pkmax_xor(vB2, o); vB3 = pkmax_xor(vB3, o);
        }
        vmA[0] = vA0; vmA[1] = vA1; vmA[2] = vA2; vmA[3] = vA3;
        vmB[0] = vB0; vmB[1] = vB1; vmB[2] = vB2; vmB[3] = vB3;
    } else {
        // --- rare slow path (either node deg>64): handle each in turn ---
        slow_node(rsA, reA, src_sorted, alpha_s, atA, WhH, lane, fl2, zA, vmA);
        slow_node(rsB, reB, src_sorted, alpha_s, atB, WhH, lane, fl2, zB, vmB);
    }

    // epilogue per node: h = vmax/z + bias, relu.
    float4 b0 = *(const float4*)(bias + fl2 * 8);
    float4 b1 = *(const float4*)(bias + fl2 * 8 + 4);
    float rzA = 1.0f / zA, rzB = 1.0f / zB;
    float h8A[8], h8B[8];
#pragma unroll
    for (int q = 0; q < 4; ++q) {
        float2 fa = __half22float2(*(__half2*)&vmA[q]);
        float2 fb = __half22float2(*(__half2*)&vmB[q]);
        h8A[2 * q] = fa.x; h8A[2 * q + 1] = fa.y;
        h8B[2 * q] = fb.x; h8B[2 * q + 1] = fb.y;
    }
    const float* bb = (const float*)&b0;   // b0,b1 contiguous? keep explicit:
    float bias8[8] = { b0.x, b0.y, b0.z, b0.w, b1.x, b1.y, b1.z, b1.w };
#pragma unroll
    for (int q = 0; q < 8; ++q) {
        h8A[q] = fmaxf(h8A[q] * rzA + bias8[q], 0.f);
        h8B[q] = fmaxf(h8B[q] * rzB + bias8[q], 0.f);
    }
    (void)bb;

    if (!HEAD) {
        if (g2 == 0) {
            float* op = outp + (size_t)dA * 64 + fl2 * 8;
            *(float4*)op = make_float4(h8A[0], h8A[1], h8A[2], h8A[3]);
            *(float4*)(op + 4) = make_float4(h8A[4], h8A[5], h8A[6], h8A[7]);
        } else if (g2 == 1) {
            float* op = outp + (size_t)dB * 64 + fl2 * 8;
            *(float4*)op = make_float4(h8B[0], h8B[1], h8B[2], h8B[3]);
            *(float4*)(op + 4) = make_float4(h8B[4], h8B[5], h8B[6], h8B[7]);
        }
    } else {
        if (g2 == 0) {
            float* sp = sh + (2 * w) * 64 + fl2 * 8;
            *(float4*)sp = make_float4(h8A[0], h8A[1], h8A[2], h8A[3]);
            *(float4*)(sp + 4) = make_float4(h8A[4], h8A[5], h8A[6], h8A[7]);
        } else if (g2 == 1) {
            float* sp = sh + (2 * w + 1) * 64 + fl2 * 8;
            *(float4*)sp = make_float4(h8B[0], h8B[1], h8B[2], h8B[3]);
            *(float4*)(sp + 4) = make_float4(h8B[4], h8B[5], h8B[6], h8B[7]);
        }
        __syncthreads();
#pragma unroll
        for (int n = 0; n < 2; ++n) {
            int dd = dA + n;
            const float* hrow = sh + (2 * w + n) * 64;
            float logit = -INFINITY;
            if (lane < N_CLS) {
                float acc = bo[lane];
#pragma unroll
                for (int k = 0; k < 64; ++k)
                    acc = fmaf(hrow[k], sWo[k * N_CLS + lane], acc);
                logit = acc;
            }
            float mx = logit;
#pragma unroll
            for (int o = 32; o; o >>= 1) mx = fmaxf(mx, __shfl_xor(mx, o, 64));
            float ex = (lane < N_CLS) ? __expf(logit - mx) : 0.f;
            float sm = ex;
#pragma unroll
            for (int o = 32; o; o >>= 1) sm += __shfl_xor(sm, o, 64);
            float lse = mx + __logf(sm);
            if (lane < N_CLS) outp[(size_t)dd * N_CLS + lane] = logit - lse;
        }
    }
}

extern "C" void kernel_launch(void* const* d_in, const int* in_sizes, int n_in,
                              void* d_out, int out_size, void* d_ws, size_t ws_size,
                              hipStream_t stream) {
    const float* x   = (const float*)d_in[0];
    const void*  ei  = d_in[1];
    const float* W1  = (const float*)d_in[2];
    const float* aW1 = (const float*)d_in[3];
    const float* ab1 = (const float*)d_in[4];
    const float* b1  = (const float*)d_in[5];
    const float* W2  = (const float*)d_in[6];
    const float* aW2 = (const float*)d_in[7];
    const float* ab2 = (const float*)d_in[8];
    const float* b2  = (const float*)d_in[9];
    const float* Wo  = (const float*)d_in[10];
    const float* bo  = (const float*)d_in[11];
    float* out = (float*)d_out;

    char* ws = (char*)d_ws;
    size_t off = 0;
    auto alloc = [&](size_t bytes) {
        void* p = ws + off;
        off += (bytes + 255) & ~(size_t)255;
        return p;
    };
    int*   src32      = (int*)alloc((size_t)N_EDGES * 4);
    int*   dst32      = (int*)alloc((size_t)N_EDGES * 4);
    int*   deg        = (int*)alloc((size_t)N_NODES * 4);
    int*   rowptr     = (int*)alloc((size_t)(N_NODES + 1) * 4);
    int*   cursor     = (int*)alloc((size_t)N_NODES * 4);
    int*   partials   = (int*)alloc((size_t)SCAN_B * 4);
    int*   src_sorted = (int*)alloc((size_t)E_TOT * 4);
    H4*    WhH        = (H4*)alloc((size_t)N_NODES * 64 * 2);
    float* h_mid      = (float*)alloc((size_t)N_NODES * 64 * 4);
    float* alpha_s    = (float*)alloc((size_t)N_NODES * 4);
    float* alpha_t    = (float*)alloc((size_t)N_NODES * 4);

    const int B = 256;
    int gEdgeE = (N_EDGES + B - 1) / B;
    int gEdgeT = (E_TOT + B - 1) / B;
    dim3 blk2(64, 4);
    int gRow  = N_NODES / 8;            // 6250, exact (2 nodes/wave)
    int gGemm = (N_NODES + 63) / 64;    // 782

    // ---- CSR build
    hipMemsetAsync(deg, 0, (size_t)N_NODES * 4, stream);
    k_convert<<<gEdgeE, B, 0, stream>>>(ei, src32, dst32, deg);
    k_scan1<<<N_CHUNKS, SCAN_B, 0, stream>>>(deg, rowptr, partials);
    k_scan2<<<1, SCAN_B, 0, stream>>>(partials);
    k_scan3<<<N_CHUNKS, SCAN_B, 0, stream>>>(partials, rowptr, cursor);
    k_scatter_csr<<<gEdgeT, B, 0, stream>>>(src32, dst32, cursor, src_sorted);

    // ---- layer 1
    k_gemm_alpha<128><<<gGemm, 256, 0, stream>>>(x, W1, aW1, WhH, alpha_s, alpha_t);
    k_node_aggr<0><<<gRow, blk2, 0, stream>>>(rowptr, src_sorted, alpha_s, alpha_t,
                                              ab1, WhH, b1, nullptr, nullptr, h_mid);

    // ---- layer 2 (+ fused output head)
    k_gemm_alpha<64><<<gGemm, 256, 0, stream>>>(h_mid, W2, aW2, WhH, alpha_s, alpha_t);
    k_node_aggr<1><<<gRow, blk2, 0, stream>>>(rowptr, src_sorted, alpha_s, alpha_t,
                                              ab2, WhH, b2, Wo, bo, out);
}

// Round 10
// 173.287 us; speedup vs baseline: 3.8313x; 1.1882x over previous
//
#include <hip/hip_runtime.h>
#include <hip/hip_fp16.h>
#include <math.h>

#define N_NODES 50000
#define N_EDGES 800000
#define E_TOT   (N_EDGES + N_NODES)
#define D_HID   64
#define N_CLS   40
#define SCAN_B  256
#define N_CHUNKS ((N_NODES + SCAN_B - 1) / SCAN_B)   // 196
#define NB      391                                   // dst buckets of 128 nodes
#define EPB     4096                                  // edges per pass-C block

struct __align__(8) H4 { __half2 a, b; };   // 4 halves = 8 bytes

// ROCm 7.2 hip_fp16.h lacks __hmax2/__hmul2 — emit VOP3P packed ops directly.
__device__ __forceinline__ unsigned pk_max_f16(unsigned a, unsigned b) {
    unsigned r;
    asm("v_pk_max_f16 %0, %1, %2" : "=v"(r) : "v"(a), "v"(b));
    return r;
}
__device__ __forceinline__ unsigned pk_mul_f16(unsigned a, unsigned b) {
    unsigned r;
    asm("v_pk_mul_f16 %0, %1, %2" : "=v"(r) : "v"(a), "v"(b));
    return r;
}
__device__ __forceinline__ unsigned pkmax_xor(unsigned v, int o) {
    unsigned t = __shfl_xor((int)v, o, 64);
    return pk_max_f16(v, t);
}

// ---- convert (+ inline dtype detect, + degree histogram) -------------------
__global__ void k_convert(const void* ei, int2* __restrict__ pairs,
                          int* __restrict__ deg) {
    __shared__ int s_is32;
    if (threadIdx.x == 0) s_is32 = 0;
    __syncthreads();
    const int* p32 = (const int*)ei;
    if (p32[2 * threadIdx.x + 1] != 0) atomicOr(&s_is32, 1);
    __syncthreads();
    int e = blockIdx.x * 256 + threadIdx.x;
    if (e >= N_EDGES) return;
    int s, d;
    if (s_is32) {
        s = p32[e]; d = p32[N_EDGES + e];
    } else {
        const long long* p64 = (const long long*)ei;
        s = (int)p64[e]; d = (int)p64[N_EDGES + e];
    }
    pairs[e] = make_int2(s, d);
    atomicAdd(&deg[d], 1);
}

// ---- CSR build: scan --------------------------------------------------------
__device__ __forceinline__ int block_scan_incl(int v, int* wsum) {
    int lane = threadIdx.x & 63, w = threadIdx.x >> 6;
    int s = v;
#pragma unroll
    for (int d = 1; d < 64; d <<= 1) {
        int t = __shfl_up(s, d, 64);
        if (lane >= d) s += t;
    }
    if (lane == 63) wsum[w] = s;
    __syncthreads();
    int add = 0;
    for (int ww = 0; ww < (threadIdx.x >> 6); ++ww) add += wsum[ww];
    return s + add;
}

__global__ void k_scan1(const int* __restrict__ deg, int* __restrict__ rowptr,
                        int* __restrict__ partials) {
    __shared__ int wsum[4];
    int i = blockIdx.x * SCAN_B + threadIdx.x;
    int v = (i < N_NODES) ? deg[i] + 1 : 0;      // +1 = self loop
    int s = block_scan_incl(v, wsum);
    if (i < N_NODES) rowptr[i] = s - v;          // block-local exclusive
    if (threadIdx.x == SCAN_B - 1) partials[blockIdx.x] = s;
}

__global__ void k_scan2(int* partials) {
    __shared__ int wsum[4];
    int i = threadIdx.x;
    int v = (i < N_CHUNKS) ? partials[i] : 0;
    int s = block_scan_incl(v, wsum);
    if (i < N_CHUNKS) partials[i] = s - v;       // exclusive
}

__global__ void k_scan3(const int* __restrict__ partials, int* __restrict__ rowptr) {
    int i = blockIdx.x * SCAN_B + threadIdx.x;
    if (i < N_NODES) rowptr[i] += partials[blockIdx.x];
    if (blockIdx.x == 0 && threadIdx.x == 0) rowptr[N_NODES] = E_TOT;
}

// bucket cursor init: pair-array base of bucket b is rowptr[128b] - 128b
__global__ void k_bucket_init(const int* __restrict__ rowptr, int* __restrict__ bcursor) {
    int b = threadIdx.x;
    if (b < NB) bcursor[b] = rowptr[b << 7] - (b << 7);
}

// ---- pass C: bucket-grouping scatter (LDS rank + one atomic per blk/bkt) ---
__global__ __launch_bounds__(256) void k_bucket_scatter(
        const int2* __restrict__ pairs_in, int* __restrict__ bcursor,
        int2* __restrict__ pairs_bkt) {
    __shared__ int counts[512];
    __shared__ int gbase[512];
    int t = threadIdx.x;
    counts[t] = 0; counts[t + 256] = 0;
    __syncthreads();
    int base = blockIdx.x * EPB;
    int nEdge = min(EPB, N_EDGES - base);
    int2 pr0, pr1, pr2, pr3, pr4, pr5, pr6, pr7, pr8, pr9, prA, prB, prC, prD, prE, prF;
    int rk[16], bk[16];
#define LOADI(i, pv) { int idx = t + (i) * 256;                        \
        if (idx < nEdge) { pv = pairs_in[base + idx];                   \
            bk[i] = pv.y >> 7; rk[i] = atomicAdd(&counts[bk[i]], 1); } }
    LOADI(0, pr0) LOADI(1, pr1) LOADI(2, pr2) LOADI(3, pr3)
    LOADI(4, pr4) LOADI(5, pr5) LOADI(6, pr6) LOADI(7, pr7)
    LOADI(8, pr8) LOADI(9, pr9) LOADI(10, prA) LOADI(11, prB)
    LOADI(12, prC) LOADI(13, prD) LOADI(14, prE) LOADI(15, prF)
#undef LOADI
    __syncthreads();
    if (counts[t])       gbase[t]       = atomicAdd(&bcursor[t], counts[t]);
    if (counts[t + 256]) gbase[t + 256] = atomicAdd(&bcursor[t + 256], counts[t + 256]);
    __syncthreads();
#define STOREI(i, pv) { int idx = t + (i) * 256;                        \
        if (idx < nEdge) pairs_bkt[gbase[bk[i]] + rk[i]] = pv; }
    STOREI(0, pr0) STOREI(1, pr1) STOREI(2, pr2) STOREI(3, pr3)
    STOREI(4, pr4) STOREI(5, pr5) STOREI(6, pr6) STOREI(7, pr7)
    STOREI(8, pr8) STOREI(9, pr9) STOREI(10, prA) STOREI(11, prB)
    STOREI(12, prC) STOREI(13, prD) STOREI(14, prE) STOREI(15, prF)
#undef STOREI
}

// ---- pass D: within-bucket placement (LDS cursors, L2-resident writes) -----
__global__ __launch_bounds__(256) void k_bucket_place(
        const int2* __restrict__ pairs_bkt, const int* __restrict__ rowptr,
        int* __restrict__ src_sorted) {
    __shared__ int cur[128];
    int b = blockIdx.x, t = threadIdx.x;
    int d0 = b << 7;
    int dEnd = min(d0 + 128, N_NODES);
    if (t < 128) {
        int d = d0 + t;
        if (d < dEnd) {
            int r = rowptr[d];
            src_sorted[r] = d;            // self loop (order within segment free)
            cur[t] = r + 1;
        }
    }
    __syncthreads();
    int pbase = rowptr[d0] - d0;
    int pend  = rowptr[dEnd] - dEnd;
    for (int idx = pbase + t; idx < pend; idx += 256) {
        int2 p = pairs_bkt[idx];
        int pos = atomicAdd(&cur[p.y - d0], 1);
        src_sorted[pos] = p.x;
    }
}

// ---- register-tiled GEMM: WhH(fp16) = x@W (+ alpha_s/alpha_t dots) ---------
template<int K>
__global__ __launch_bounds__(256, 4) void k_gemm_alpha(
        const float* __restrict__ x, const float* __restrict__ W,
        const float* __restrict__ aW,
        H4* __restrict__ WhH,
        float* __restrict__ alpha_s, float* __restrict__ alpha_t) {
    __shared__ float Wc[32][68];
    __shared__ float xT[32][68];
    int tid = threadIdx.x;
    int tx2 = tid & 15, ty2 = tid >> 4;
    int rowBase = blockIdx.x * 64;

    float acc[4][4];
#pragma unroll
    for (int r = 0; r < 4; ++r)
#pragma unroll
        for (int c = 0; c < 4; ++c) acc[r][c] = 0.f;

    int rr = tid >> 2;            // 0..63 : x row this thread stages
    int kk = (tid & 3) * 8;       // 0,8,16,24 : k-offset this thread stages
    int srcRow = min(rowBase + rr, N_NODES - 1);
    const float* xrow = x + (size_t)srcRow * K;
    int wrow = tid >> 3;          // 0..31 : W row this thread stages
    int wcol = (tid & 7) * 8;     // 0..56

    for (int kb = 0; kb < K; kb += 32) {
        __syncthreads();          // previous chunk fully consumed
        float4 a0 = *(const float4*)(xrow + kb + kk);
        float4 a1 = *(const float4*)(xrow + kb + kk + 4);
        float4 w0 = *(const float4*)(W + (size_t)(kb + wrow) * 64 + wcol);
        float4 w1 = *(const float4*)(W + (size_t)(kb + wrow) * 64 + wcol + 4);
        xT[kk + 0][rr] = a0.x; xT[kk + 1][rr] = a0.y;
        xT[kk + 2][rr] = a0.z; xT[kk + 3][rr] = a0.w;
        xT[kk + 4][rr] = a1.x; xT[kk + 5][rr] = a1.y;
        xT[kk + 6][rr] = a1.z; xT[kk + 7][rr] = a1.w;
        *(float4*)&Wc[wrow][wcol] = w0;
        *(float4*)&Wc[wrow][wcol + 4] = w1;
        __syncthreads();
#pragma unroll 8
        for (int k2 = 0; k2 < 32; ++k2) {
            float4 xa = *(const float4*)&xT[k2][ty2 * 4];
            float4 wb = *(const float4*)&Wc[k2][tx2 * 4];
            acc[0][0] = fmaf(xa.x, wb.x, acc[0][0]);
            acc[0][1] = fmaf(xa.x, wb.y, acc[0][1]);
            acc[0][2] = fmaf(xa.x, wb.z, acc[0][2]);
            acc[0][3] = fmaf(xa.x, wb.w, acc[0][3]);
            acc[1][0] = fmaf(xa.y, wb.x, acc[1][0]);
            acc[1][1] = fmaf(xa.y, wb.y, acc[1][1]);
            acc[1][2] = fmaf(xa.y, wb.z, acc[1][2]);
            acc[1][3] = fmaf(xa.y, wb.w, acc[1][3]);
            acc[2][0] = fmaf(xa.z, wb.x, acc[2][0]);
            acc[2][1] = fmaf(xa.z, wb.y, acc[2][1]);
            acc[2][2] = fmaf(xa.z, wb.z, acc[2][2]);
            acc[2][3] = fmaf(xa.z, wb.w, acc[2][3]);
            acc[3][0] = fmaf(xa.w, wb.x, acc[3][0]);
            acc[3][1] = fmaf(xa.w, wb.y, acc[3][1]);
            acc[3][2] = fmaf(xa.w, wb.z, acc[3][2]);
            acc[3][3] = fmaf(xa.w, wb.w, acc[3][3]);
        }
    }

    // epilogue: fp16 Wh store + per-row attention dots (f32)
    float4 as4 = *(const float4*)(aW + tx2 * 4);
    float4 at4 = *(const float4*)(aW + 64 + tx2 * 4);
#pragma unroll
    for (int r = 0; r < 4; ++r) {
        int row = rowBase + ty2 * 4 + r;
        if (row >= N_NODES) continue;
        H4 hv;
        hv.a = __floats2half2_rn(acc[r][0], acc[r][1]);
        hv.b = __floats2half2_rn(acc[r][2], acc[r][3]);
        WhH[(size_t)row * 16 + tx2] = hv;
        float ps = acc[r][0] * as4.x + acc[r][1] * as4.y + acc[r][2] * as4.z + acc[r][3] * as4.w;
        float pt = acc[r][0] * at4.x + acc[r][1] * at4.y + acc[r][2] * at4.z + acc[r][3] * at4.w;
#pragma unroll
        for (int o = 1; o < 16; o <<= 1) {
            ps += __shfl_xor(ps, o, 64);
            pt += __shfl_xor(pt, o, 64);
        }
        if (tx2 == 0) { alpha_s[row] = ps; alpha_t[row] = pt; }
    }
}

// ---- slow path helper (deg > 64): chunked two-pass, scalar fp16 gather -----
__device__ void slow_node(int rs, int re, const int* __restrict__ src_sorted,
                          const float* __restrict__ alpha_s, float at,
                          const H4* __restrict__ WhH, int lane, int fl2,
                          float& z, unsigned vm[4]) {
    float m = -INFINITY;
    for (int base = rs; base < re; base += 64) {
        int idx = base + lane;
        float sim = -INFINITY;
        if (idx < re) {
            int sv = src_sorted[idx];
            float t = alpha_s[sv] + at;
            sim = t > 0.f ? t : 0.2f * t;
        }
#pragma unroll
        for (int o = 32; o; o >>= 1) sim = fmaxf(sim, __shfl_xor(sim, o, 64));
        m = fmaxf(m, sim);
    }
    z = 0.f;
    float vsc = -INFINITY;
    for (int base = rs; base < re; base += 64) {
        int idx = base + lane;
        int cnt = min(64, re - base);
        int svv = 0;
        float ev = 0.f;
        if (idx < re) {
            svv = src_sorted[idx];
            float t = alpha_s[svv] + at;
            t = t > 0.f ? t : 0.2f * t;
            ev = __expf(t - m);
        }
        float sz = ev;
#pragma unroll
        for (int o = 32; o; o >>= 1) sz += __shfl_xor(sz, o, 64);
        z += sz;
        for (int j = 0; j < cnt; ++j) {
            int sj = __shfl(svv, j, 64);
            float ej = __shfl(ev, j, 64);
            float v = __half2float(((const __half*)WhH)[(size_t)sj * 64 + lane]);
            vsc = fmaxf(vsc, ej * v);
        }
    }
#pragma unroll
    for (int q = 0; q < 4; ++q) {
        float a0 = __shfl(vsc, fl2 * 8 + 2 * q, 64);
        float a1 = __shfl(vsc, fl2 * 8 + 2 * q + 1, 64);
        __half2 p = __floats2half2_rn(a0, a1);
        vm[q] = *(unsigned*)&p;
    }
}

// ---- per-dst-node fused: attention softmax + scatter-max aggregation -------
// TWO nodes per wave (A,B): doubles outstanding misses & hides the dependent
// shfl-reduce chains of one node under the other's gather loads.
template<int HEAD>
__global__ void k_node_aggr(const int* __restrict__ rowptr, const int* __restrict__ src_sorted,
                            const float* __restrict__ alpha_s, const float* __restrict__ alpha_t,
                            const float* __restrict__ ab, const H4* __restrict__ WhH,
                            const float* __restrict__ bias,
                            const float* __restrict__ Wo, const float* __restrict__ bo,
                            float* __restrict__ outp) {
    __shared__ float sWo[HEAD ? 64 * N_CLS : 1];
    __shared__ float sh[HEAD ? 8 * 64 : 1];
    int lane = threadIdx.x, w = threadIdx.y;
    if (HEAD) {
        int tid = w * 64 + lane;
        for (int i = tid; i < 64 * N_CLS; i += 256) sWo[i] = Wo[i];
    }
    int dA = blockIdx.x * 8 + w * 2;       // grid exact: 6250*8 == N_NODES
    int dB = dA + 1;
    int rsA = rowptr[dA], reA = rowptr[dA + 1];
    int rsB = rowptr[dB], reB = rowptr[dB + 1];
    int degA = reA - rsA, degB = reB - rsB;
    float abv = ab[0];
    float atA = alpha_t[dA] + abv;
    float atB = alpha_t[dB] + abv;
    int g2 = lane >> 3, fl2 = lane & 7;
    const char* whb = (const char*)WhH;

    float zA, zB;
    unsigned vmA[4], vmB[4];

    if (degA <= 64 && degB <= 64) {
        // --- dual fast path ---
        int svA = src_sorted[rsA + min(lane, degA - 1)];
        int svB = src_sorted[rsB + min(lane, degB - 1)];
        float tA = alpha_s[svA] + atA; tA = tA > 0.f ? tA : 0.2f * tA;
        float tB = alpha_s[svB] + atB; tB = tB > 0.f ? tB : 0.2f * tB;
        float evA = __expf(tA);            // no max-subtract: |t| is O(1)
        float evB = __expf(tB);
        float zzA = (lane < degA) ? evA : 0.f;
        float zzB = (lane < degB) ? evB : 0.f;
#pragma unroll
        for (int o = 32; o; o >>= 1) {
            zzA += __shfl_xor(zzA, o, 64);
            zzB += __shfl_xor(zzB, o, 64);
        }
        zA = zzA; zB = zzB;
        int ofsA = svA * 128, ofsB = svB * 128;   // byte offsets of fp16 rows

        const unsigned NEGINF2 = 0xFC00FC00u;     // {-inf,-inf} fp16
        unsigned vA0 = NEGINF2, vA1 = NEGINF2, vA2 = NEGINF2, vA3 = NEGINF2;
        unsigned vB0 = NEGINF2, vB1 = NEGINF2, vB2 = NEGINF2, vB3 = NEGINF2;
#define ROUND(ev, ofs, deg, v0, v1, v2, v3, r) { \
        int j = (r) * 8 + g2; j = j < (deg) ? j : (deg) - 1;              \
        float ej = __shfl((ev), j, 64);                                   \
        int ro = __shfl((ofs), j, 64);                                    \
        uint4 hv = *(const uint4*)(whb + ro + fl2 * 16);                  \
        __half2 ejh = __float2half2_rn(ej);                               \
        unsigned ej2 = *(unsigned*)&ejh;                                  \
        v0 = pk_max_f16(v0, pk_mul_f16(ej2, hv.x));                       \
        v1 = pk_max_f16(v1, pk_mul_f16(ej2, hv.y));                       \
        v2 = pk_max_f16(v2, pk_mul_f16(ej2, hv.z));                       \
        v3 = pk_max_f16(v3, pk_mul_f16(ej2, hv.w)); }
#define RA(r) ROUND(evA, ofsA, degA, vA0, vA1, vA2, vA3, r)
#define RB(r) ROUND(evB, ofsB, degB, vB0, vB1, vB2, vB3, r)

        RA(0) RB(0) RA(1) RB(1)
        if (degA > 16) { RA(2) RA(3) }
        if (degB > 16) { RB(2) RB(3) }
        if (degA > 32) { RA(4) RA(5) RA(6) RA(7) }
        if (degB > 32) { RB(4) RB(5) RB(6) RB(7) }
#undef RA
#undef RB
#undef ROUND
#pragma unroll
        for (int o = 8; o <= 32; o <<= 1) {
            vA0 = pkmax_xor(vA0, o); vA1 = pkmax_xor(vA1, o);
            vA2 = pkmax_xor(vA2, o); vA3 = pkmax_xor(vA3, o);
            vB0 = pkmax_xor(vB0, o); vB1 = pkmax_xor(vB1, o);
            vB2 = pkmax_xor(vB2, o); vB3 = pkmax_xor(vB3, o);
        }
        vmA[0] = vA0; vmA[1] = vA1; vmA[2] = vA2; vmA[3] = vA3;
        vmB[0] = vB0; vmB[1] = vB1; vmB[2] = vB2; vmB[3] = vB3;
    } else {
        slow_node(rsA, reA, src_sorted, alpha_s, atA, WhH, lane, fl2, zA, vmA);
        slow_node(rsB, reB, src_sorted, alpha_s, atB, WhH, lane, fl2, zB, vmB);
    }

    // epilogue per node: h = vmax/z + bias, relu.
    float4 b0 = *(const float4*)(bias + fl2 * 8);
    float4 b1 = *(const float4*)(bias + fl2 * 8 + 4);
    float rzA = 1.0f / zA, rzB = 1.0f / zB;
    float h8A[8], h8B[8];
#pragma unroll
    for (int q = 0; q < 4; ++q) {
        float2 fa = __half22float2(*(__half2*)&vmA[q]);
        float2 fb = __half22float2(*(__half2*)&vmB[q]);
        h8A[2 * q] = fa.x; h8A[2 * q + 1] = fa.y;
        h8B[2 * q] = fb.x; h8B[2 * q + 1] = fb.y;
    }
    float bias8[8] = { b0.x, b0.y, b0.z, b0.w, b1.x, b1.y, b1.z, b1.w };
#pragma unroll
    for (int q = 0; q < 8; ++q) {
        h8A[q] = fmaxf(h8A[q] * rzA + bias8[q], 0.f);
        h8B[q] = fmaxf(h8B[q] * rzB + bias8[q], 0.f);
    }

    if (!HEAD) {
        if (g2 == 0) {
            float* op = outp + (size_t)dA * 64 + fl2 * 8;
            *(float4*)op = make_float4(h8A[0], h8A[1], h8A[2], h8A[3]);
            *(float4*)(op + 4) = make_float4(h8A[4], h8A[5], h8A[6], h8A[7]);
        } else if (g2 == 1) {
            float* op = outp + (size_t)dB * 64 + fl2 * 8;
            *(float4*)op = make_float4(h8B[0], h8B[1], h8B[2], h8B[3]);
            *(float4*)(op + 4) = make_float4(h8B[4], h8B[5], h8B[6], h8B[7]);
        }
    } else {
        if (g2 == 0) {
            float* sp = sh + (2 * w) * 64 + fl2 * 8;
            *(float4*)sp = make_float4(h8A[0], h8A[1], h8A[2], h8A[3]);
            *(float4*)(sp + 4) = make_float4(h8A[4], h8A[5], h8A[6], h8A[7]);
        } else if (g2 == 1) {
            float* sp = sh + (2 * w + 1) * 64 + fl2 * 8;
            *(float4*)sp = make_float4(h8B[0], h8B[1], h8B[2], h8B[3]);
            *(float4*)(sp + 4) = make_float4(h8B[4], h8B[5], h8B[6], h8B[7]);
        }
        __syncthreads();
#pragma unroll
        for (int n = 0; n < 2; ++n) {
            int dd = dA + n;
            const float* hrow = sh + (2 * w + n) * 64;
            float logit = -INFINITY;
            if (lane < N_CLS) {
                float acc = bo[lane];
#pragma unroll
                for (int k = 0; k < 64; ++k)
                    acc = fmaf(hrow[k], sWo[k * N_CLS + lane], acc);
                logit = acc;
            }
            float mx = logit;
#pragma unroll
            for (int o = 32; o; o >>= 1) mx = fmaxf(mx, __shfl_xor(mx, o, 64));
            float ex = (lane < N_CLS) ? __expf(logit - mx) : 0.f;
            float sm = ex;
#pragma unroll
            for (int o = 32; o; o >>= 1) sm += __shfl_xor(sm, o, 64);
            float lse = mx + __logf(sm);
            if (lane < N_CLS) outp[(size_t)dd * N_CLS + lane] = logit - lse;
        }
    }
}

extern "C" void kernel_launch(void* const* d_in, const int* in_sizes, int n_in,
                              void* d_out, int out_size, void* d_ws, size_t ws_size,
                              hipStream_t stream) {
    const float* x   = (const float*)d_in[0];
    const void*  ei  = d_in[1];
    const float* W1  = (const float*)d_in[2];
    const float* aW1 = (const float*)d_in[3];
    const float* ab1 = (const float*)d_in[4];
    const float* b1  = (const float*)d_in[5];
    const float* W2  = (const float*)d_in[6];
    const float* aW2 = (const float*)d_in[7];
    const float* ab2 = (const float*)d_in[8];
    const float* b2  = (const float*)d_in[9];
    const float* Wo  = (const float*)d_in[10];
    const float* bo  = (const float*)d_in[11];
    float* out = (float*)d_out;

    char* ws = (char*)d_ws;
    size_t off = 0;
    auto alloc = [&](size_t bytes) {
        void* p = ws + off;
        off += (bytes + 255) & ~(size_t)255;
        return p;
    };
    int2*  pairs      = (int2*)alloc((size_t)N_EDGES * 8);
    int2*  pairs_bkt  = (int2*)alloc((size_t)N_EDGES * 8);
    int*   deg        = (int*)alloc((size_t)N_NODES * 4);
    int*   rowptr     = (int*)alloc((size_t)(N_NODES + 1) * 4);
    int*   bcursor    = (int*)alloc((size_t)512 * 4);
    int*   partials   = (int*)alloc((size_t)SCAN_B * 4);
    int*   src_sorted = (int*)alloc((size_t)E_TOT * 4);
    H4*    WhH        = (H4*)alloc((size_t)N_NODES * 64 * 2);
    float* h_mid      = (float*)alloc((size_t)N_NODES * 64 * 4);
    float* alpha_s    = (float*)alloc((size_t)N_NODES * 4);
    float* alpha_t    = (float*)alloc((size_t)N_NODES * 4);

    const int B = 256;
    int gEdgeE = (N_EDGES + B - 1) / B;
    int gPassC = (N_EDGES + EPB - 1) / EPB;   // 196
    dim3 blk2(64, 4);
    int gRow  = N_NODES / 8;            // 6250, exact (2 nodes/wave)
    int gGemm = (N_NODES + 63) / 64;    // 782

    // ---- CSR build (two-level counting sort)
    hipMemsetAsync(deg, 0, (size_t)N_NODES * 4, stream);
    k_convert<<<gEdgeE, B, 0, stream>>>(ei, pairs, deg);
    k_scan1<<<N_CHUNKS, SCAN_B, 0, stream>>>(deg, rowptr, partials);
    k_scan2<<<1, SCAN_B, 0, stream>>>(partials);
    k_scan3<<<N_CHUNKS, SCAN_B, 0, stream>>>(partials, rowptr);
    k_bucket_init<<<1, 512, 0, stream>>>(rowptr, bcursor);
    k_bucket_scatter<<<gPassC, B, 0, stream>>>(pairs, bcursor, pairs_bkt);
    k_bucket_place<<<NB, B, 0, stream>>>(pairs_bkt, rowptr, src_sorted);

    // ---- layer 1
    k_gemm_alpha<128><<<gGemm, 256, 0, stream>>>(x, W1, aW1, WhH, alpha_s, alpha_t);
    k_node_aggr<0><<<gRow, blk2, 0, stream>>>(rowptr, src_sorted, alpha_s, alpha_t,
                                              ab1, WhH, b1, nullptr, nullptr, h_mid);

    // ---- layer 2 (+ fused output head)
    k_gemm_alpha<64><<<gGemm, 256, 0, stream>>>(h_mid, W2, aW2, WhH, alpha_s, alpha_t);
    k_node_aggr<1><<<gRow, blk2, 0, stream>>>(rowptr, src_sorted, alpha_s, alpha_t,
                                              ab2, WhH, b2, Wo, bo, out);
}

// Round 11
// 162.891 us; speedup vs baseline: 4.0758x; 1.0638x over previous
//
#include <hip/hip_runtime.h>
#include <hip/hip_fp16.h>
#include <math.h>

#define N_NODES 50000
#define N_EDGES 800000
#define E_TOT   (N_EDGES + N_NODES)
#define D_HID   64
#define N_CLS   40
#define SCAN_B  256
#define N_CHUNKS ((N_NODES + SCAN_B - 1) / SCAN_B)   // 196
#define NB      391                                   // dst buckets of 128 nodes
#define EPB     4096                                  // edges per pass-C block

struct __align__(8) H4 { __half2 a, b; };   // 4 halves = 8 bytes

typedef short bf16x8 __attribute__((ext_vector_type(8)));
typedef float f32x4  __attribute__((ext_vector_type(4)));

// ROCm 7.2 hip_fp16.h lacks __hmax2/__hmul2 — emit VOP3P packed ops directly.
__device__ __forceinline__ unsigned pk_max_f16(unsigned a, unsigned b) {
    unsigned r;
    asm("v_pk_max_f16 %0, %1, %2" : "=v"(r) : "v"(a), "v"(b));
    return r;
}
__device__ __forceinline__ unsigned pk_mul_f16(unsigned a, unsigned b) {
    unsigned r;
    asm("v_pk_mul_f16 %0, %1, %2" : "=v"(r) : "v"(a), "v"(b));
    return r;
}
__device__ __forceinline__ unsigned pkmax_xor(unsigned v, int o) {
    unsigned t = __shfl_xor((int)v, o, 64);
    return pk_max_f16(v, t);
}

// manual f32 -> bf16 round-to-nearest-even (avoid header roulette)
__device__ __forceinline__ unsigned short f2bf(float f) {
    unsigned u = __float_as_uint(f);
    u += 0x7FFFu + ((u >> 16) & 1);
    return (unsigned short)(u >> 16);
}
__device__ __forceinline__ unsigned pk_bf(float a, float b) {
    return (unsigned)f2bf(a) | ((unsigned)f2bf(b) << 16);
}

// ---- convert (+ inline dtype detect, + degree histogram) -------------------
__global__ void k_convert(const void* ei, int2* __restrict__ pairs,
                          int* __restrict__ deg) {
    __shared__ int s_is32;
    if (threadIdx.x == 0) s_is32 = 0;
    __syncthreads();
    const int* p32 = (const int*)ei;
    if (p32[2 * threadIdx.x + 1] != 0) atomicOr(&s_is32, 1);
    __syncthreads();
    int e = blockIdx.x * 256 + threadIdx.x;
    if (e >= N_EDGES) return;
    int s, d;
    if (s_is32) {
        s = p32[e]; d = p32[N_EDGES + e];
    } else {
        const long long* p64 = (const long long*)ei;
        s = (int)p64[e]; d = (int)p64[N_EDGES + e];
    }
    pairs[e] = make_int2(s, d);
    atomicAdd(&deg[d], 1);
}

// ---- CSR build: scan --------------------------------------------------------
__device__ __forceinline__ int block_scan_incl(int v, int* wsum) {
    int lane = threadIdx.x & 63, w = threadIdx.x >> 6;
    int s = v;
#pragma unroll
    for (int d = 1; d < 64; d <<= 1) {
        int t = __shfl_up(s, d, 64);
        if (lane >= d) s += t;
    }
    if (lane == 63) wsum[w] = s;
    __syncthreads();
    int add = 0;
    for (int ww = 0; ww < (threadIdx.x >> 6); ++ww) add += wsum[ww];
    return s + add;
}

__global__ void k_scan1(const int* __restrict__ deg, int* __restrict__ rowptr,
                        int* __restrict__ partials) {
    __shared__ int wsum[4];
    int i = blockIdx.x * SCAN_B + threadIdx.x;
    int v = (i < N_NODES) ? deg[i] + 1 : 0;      // +1 = self loop
    int s = block_scan_incl(v, wsum);
    if (i < N_NODES) rowptr[i] = s - v;          // block-local exclusive
    if (threadIdx.x == SCAN_B - 1) partials[blockIdx.x] = s;
}

__global__ void k_scan2(int* partials) {
    __shared__ int wsum[4];
    int i = threadIdx.x;
    int v = (i < N_CHUNKS) ? partials[i] : 0;
    int s = block_scan_incl(v, wsum);
    if (i < N_CHUNKS) partials[i] = s - v;       // exclusive
}

__global__ void k_scan3(const int* __restrict__ partials, int* __restrict__ rowptr) {
    int i = blockIdx.x * SCAN_B + threadIdx.x;
    if (i < N_NODES) rowptr[i] += partials[blockIdx.x];
    if (blockIdx.x == 0 && threadIdx.x == 0) rowptr[N_NODES] = E_TOT;
}

// bucket cursor init: pair-array base of bucket b is rowptr[128b] - 128b
__global__ void k_bucket_init(const int* __restrict__ rowptr, int* __restrict__ bcursor) {
    int b = threadIdx.x;
    if (b < NB) bcursor[b] = rowptr[b << 7] - (b << 7);
}

// ---- pass C: bucket-grouping scatter (LDS rank + one atomic per blk/bkt) ---
__global__ __launch_bounds__(256) void k_bucket_scatter(
        const int2* __restrict__ pairs_in, int* __restrict__ bcursor,
        int2* __restrict__ pairs_bkt) {
    __shared__ int counts[512];
    __shared__ int gbase[512];
    int t = threadIdx.x;
    counts[t] = 0; counts[t + 256] = 0;
    __syncthreads();
    int base = blockIdx.x * EPB;
    int nEdge = min(EPB, N_EDGES - base);
    int2 pr0, pr1, pr2, pr3, pr4, pr5, pr6, pr7, pr8, pr9, prA, prB, prC, prD, prE, prF;
    int rk[16], bk[16];
#define LOADI(i, pv) { int idx = t + (i) * 256;                        \
        if (idx < nEdge) { pv = pairs_in[base + idx];                   \
            bk[i] = pv.y >> 7; rk[i] = atomicAdd(&counts[bk[i]], 1); } }
    LOADI(0, pr0) LOADI(1, pr1) LOADI(2, pr2) LOADI(3, pr3)
    LOADI(4, pr4) LOADI(5, pr5) LOADI(6, pr6) LOADI(7, pr7)
    LOADI(8, pr8) LOADI(9, pr9) LOADI(10, prA) LOADI(11, prB)
    LOADI(12, prC) LOADI(13, prD) LOADI(14, prE) LOADI(15, prF)
#undef LOADI
    __syncthreads();
    if (counts[t])       gbase[t]       = atomicAdd(&bcursor[t], counts[t]);
    if (counts[t + 256]) gbase[t + 256] = atomicAdd(&bcursor[t + 256], counts[t + 256]);
    __syncthreads();
#define STOREI(i, pv) { int idx = t + (i) * 256;                        \
        if (idx < nEdge) pairs_bkt[gbase[bk[i]] + rk[i]] = pv; }
    STOREI(0, pr0) STOREI(1, pr1) STOREI(2, pr2) STOREI(3, pr3)
    STOREI(4, pr4) STOREI(5, pr5) STOREI(6, pr6) STOREI(7, pr7)
    STOREI(8, pr8) STOREI(9, pr9) STOREI(10, prA) STOREI(11, prB)
    STOREI(12, prC) STOREI(13, prD) STOREI(14, prE) STOREI(15, prF)
#undef STOREI
}

// ---- pass D: within-bucket placement (LDS cursors, L2-resident writes) -----
__global__ __launch_bounds__(256) void k_bucket_place(
        const int2* __restrict__ pairs_bkt, const int* __restrict__ rowptr,
        int* __restrict__ src_sorted) {
    __shared__ int cur[128];
    int b = blockIdx.x, t = threadIdx.x;
    int d0 = b << 7;
    int dEnd = min(d0 + 128, N_NODES);
    if (t < 128) {
        int d = d0 + t;
        if (d < dEnd) {
            int r = rowptr[d];
            src_sorted[r] = d;            // self loop (order within segment free)
            cur[t] = r + 1;
        }
    }
    __syncthreads();
    int pbase = rowptr[d0] - d0;
    int pend  = rowptr[dEnd] - dEnd;
    for (int idx = pbase + t; idx < pend; idx += 256) {
        int2 p = pairs_bkt[idx];
        int pos = atomicAdd(&cur[p.y - d0], 1);
        src_sorted[pos] = p.x;
    }
}

// ---- MFMA GEMM: WhH(fp16) = x@W (+ alpha_s/alpha_t dots) -------------------
// Block 256 = 4 waves; tile 64 rows x 64 cols; wave w owns rows w*16..+15.
// x and W staged to LDS as bf16 (x row-major, W transposed) so A/B fragments
// are single ds_read_b128. mfma_f32_16x16x32_bf16, f32 accumulate.
// Frag layouts (m89-verified): A: lane l holds xb[l%16][(l/16)*8+j];
// B: wt[col=l%16][(l/16)*8+j]; D: row=4*(l/16)+reg, col=l%16.
template<int K>
__global__ __launch_bounds__(256) void k_gemm_alpha(
        const float* __restrict__ x, const float* __restrict__ W,
        const float* __restrict__ aW,
        H4* __restrict__ WhH,
        float* __restrict__ alpha_s, float* __restrict__ alpha_t) {
    __shared__ unsigned short xb[64][K + 8];
    __shared__ unsigned short wt[64][K + 8];
    int tid = threadIdx.x;
    int rowBase = blockIdx.x * 64;

    // stage x -> xb bf16 (coalesced float4 global reads, packed uint LDS writes)
    {
        int rr = tid >> 2;                 // 0..63
        int kc = (tid & 3) * (K / 4);      // K=128: {0,32,64,96}; K=64: {0,16,32,48}
        const float* xr = x + (size_t)min(rowBase + rr, N_NODES - 1) * K + kc;
        unsigned* dst = (unsigned*)&xb[rr][kc];
#pragma unroll
        for (int j = 0; j < K / 4; j += 8) {
            float4 v0 = *(const float4*)(xr + j);
            float4 v1 = *(const float4*)(xr + j + 4);
            dst[j / 2 + 0] = pk_bf(v0.x, v0.y);
            dst[j / 2 + 1] = pk_bf(v0.z, v0.w);
            dst[j / 2 + 2] = pk_bf(v1.x, v1.y);
            dst[j / 2 + 3] = pk_bf(v1.z, v1.w);
        }
    }
    // stage W -> wt bf16 transposed: wt[n][k] = W[k*64+n]
    for (int i = tid; i < K * 64; i += 256) {
        int k = i >> 6, n = i & 63;
        wt[n][k] = f2bf(W[i]);
    }
    __syncthreads();

    int w = tid >> 6, lane = tid & 63;
    int la = lane & 15, hi = lane >> 4;

    f32x4 acc[4];
#pragma unroll
    for (int c = 0; c < 4; ++c) acc[c] = (f32x4){0.f, 0.f, 0.f, 0.f};

#pragma unroll
    for (int t = 0; t < K / 32; ++t) {
        int k0 = t * 32 + hi * 8;
        bf16x8 af = *(const bf16x8*)&xb[w * 16 + la][k0];
#pragma unroll
        for (int c = 0; c < 4; ++c) {
            bf16x8 bfr = *(const bf16x8*)&wt[c * 16 + la][k0];
            acc[c] = __builtin_amdgcn_mfma_f32_16x16x32_bf16(af, bfr, acc[c], 0, 0, 0);
        }
    }

    // epilogue: lane holds D rows 4*hi+r (r=0..3) of wave band, cols c*16+la.
    float as4[4], at4[4];
#pragma unroll
    for (int c = 0; c < 4; ++c) {
        as4[c] = aW[c * 16 + la];
        at4[c] = aW[64 + c * 16 + la];
    }
#pragma unroll
    for (int r = 0; r < 4; ++r) {
        int row = rowBase + w * 16 + hi * 4 + r;
        float ps = acc[0][r] * as4[0] + acc[1][r] * as4[1]
                 + acc[2][r] * as4[2] + acc[3][r] * as4[3];
        float pt = acc[0][r] * at4[0] + acc[1][r] * at4[1]
                 + acc[2][r] * at4[2] + acc[3][r] * at4[3];
#pragma unroll
        for (int o = 1; o < 16; o <<= 1) {
            ps += __shfl_xor(ps, o, 64);
            pt += __shfl_xor(pt, o, 64);
        }
        if (row < N_NODES) {
            __half* wr = (__half*)&WhH[(size_t)row * 16];
#pragma unroll
            for (int c = 0; c < 4; ++c)
                wr[c * 16 + la] = __float2half(acc[c][r]);
            if (la == 0) { alpha_s[row] = ps; alpha_t[row] = pt; }
        }
    }
}

// ---- slow path helper (deg > 64): chunked two-pass, scalar fp16 gather -----
__device__ void slow_node(int rs, int re, const int* __restrict__ src_sorted,
                          const float* __restrict__ alpha_s, float at,
                          const H4* __restrict__ WhH, int lane, int fl2,
                          float& z, unsigned vm[4]) {
    float m = -INFINITY;
    for (int base = rs; base < re; base += 64) {
        int idx = base + lane;
        float sim = -INFINITY;
        if (idx < re) {
            int sv = src_sorted[idx];
            float t = alpha_s[sv] + at;
            sim = t > 0.f ? t : 0.2f * t;
        }
#pragma unroll
        for (int o = 32; o; o >>= 1) sim = fmaxf(sim, __shfl_xor(sim, o, 64));
        m = fmaxf(m, sim);
    }
    z = 0.f;
    float vsc = -INFINITY;
    for (int base = rs; base < re; base += 64) {
        int idx = base + lane;
        int cnt = min(64, re - base);
        int svv = 0;
        float ev = 0.f;
        if (idx < re) {
            svv = src_sorted[idx];
            float t = alpha_s[svv] + at;
            t = t > 0.f ? t : 0.2f * t;
            ev = __expf(t - m);
        }
        float sz = ev;
#pragma unroll
        for (int o = 32; o; o >>= 1) sz += __shfl_xor(sz, o, 64);
        z += sz;
        for (int j = 0; j < cnt; ++j) {
            int sj = __shfl(svv, j, 64);
            float ej = __shfl(ev, j, 64);
            float v = __half2float(((const __half*)WhH)[(size_t)sj * 64 + lane]);
            vsc = fmaxf(vsc, ej * v);
        }
    }
#pragma unroll
    for (int q = 0; q < 4; ++q) {
        float a0 = __shfl(vsc, fl2 * 8 + 2 * q, 64);
        float a1 = __shfl(vsc, fl2 * 8 + 2 * q + 1, 64);
        __half2 p = __floats2half2_rn(a0, a1);
        vm[q] = *(unsigned*)&p;
    }
}

// ---- per-dst-node fused: attention softmax + scatter-max aggregation -------
// TWO nodes per wave (A,B): doubles outstanding misses & hides the dependent
// shfl-reduce chains of one node under the other's gather loads.
template<int HEAD>
__global__ void k_node_aggr(const int* __restrict__ rowptr, const int* __restrict__ src_sorted,
                            const float* __restrict__ alpha_s, const float* __restrict__ alpha_t,
                            const float* __restrict__ ab, const H4* __restrict__ WhH,
                            const float* __restrict__ bias,
                            const float* __restrict__ Wo, const float* __restrict__ bo,
                            float* __restrict__ outp) {
    __shared__ float sWo[HEAD ? 64 * N_CLS : 1];
    __shared__ float sh[HEAD ? 8 * 64 : 1];
    int lane = threadIdx.x, w = threadIdx.y;
    if (HEAD) {
        int tid = w * 64 + lane;
        for (int i = tid; i < 64 * N_CLS; i += 256) sWo[i] = Wo[i];
    }
    int dA = blockIdx.x * 8 + w * 2;       // grid exact: 6250*8 == N_NODES
    int dB = dA + 1;
    int rsA = rowptr[dA], reA = rowptr[dA + 1];
    int rsB = rowptr[dB], reB = rowptr[dB + 1];
    int degA = reA - rsA, degB = reB - rsB;
    float abv = ab[0];
    float atA = alpha_t[dA] + abv;
    float atB = alpha_t[dB] + abv;
    int g2 = lane >> 3, fl2 = lane & 7;
    const char* whb = (const char*)WhH;

    float zA, zB;
    unsigned vmA[4], vmB[4];

    if (degA <= 64 && degB <= 64) {
        // --- dual fast path ---
        int svA = src_sorted[rsA + min(lane, degA - 1)];
        int svB = src_sorted[rsB + min(lane, degB - 1)];
        float tA = alpha_s[svA] + atA; tA = tA > 0.f ? tA : 0.2f * tA;
        float tB = alpha_s[svB] + atB; tB = tB > 0.f ? tB : 0.2f * tB;
        float evA = __expf(tA);            // no max-subtract: |t| is O(1)
        float evB = __expf(tB);
        float zzA = (lane < degA) ? evA : 0.f;
        float zzB = (lane < degB) ? evB : 0.f;
#pragma unroll
        for (int o = 32; o; o >>= 1) {
            zzA += __shfl_xor(zzA, o, 64);
            zzB += __shfl_xor(zzB, o, 64);
        }
        zA = zzA; zB = zzB;
        int ofsA = svA * 128, ofsB = svB * 128;   // byte offsets of fp16 rows

        const unsigned NEGINF2 = 0xFC00FC00u;     // {-inf,-inf} fp16
        unsigned vA0 = NEGINF2, vA1 = NEGINF2, vA2 = NEGINF2, vA3 = NEGINF2;
        unsigned vB0 = NEGINF2, vB1 = NEGINF2, vB2 = NEGINF2, vB3 = NEGINF2;
#define ROUND(ev, ofs, deg, v0, v1, v2, v3, r) { \
        int j = (r) * 8 + g2; j = j < (deg) ? j : (deg) - 1;              \
        float ej = __shfl((ev), j, 64);                                   \
        int ro = __shfl((ofs), j, 64);                                    \
        uint4 hv = *(const uint4*)(whb + ro + fl2 * 16);                  \
        __half2 ejh = __float2half2_rn(ej);                               \
        unsigned ej2 = *(unsigned*)&ejh;                                  \
        v0 = pk_max_f16(v0, pk_mul_f16(ej2, hv.x));                       \
        v1 = pk_max_f16(v1, pk_mul_f16(ej2, hv.y));                       \
        v2 = pk_max_f16(v2, pk_mul_f16(ej2, hv.z));                       \
        v3 = pk_max_f16(v3, pk_mul_f16(ej2, hv.w)); }
#define RA(r) ROUND(evA, ofsA, degA, vA0, vA1, vA2, vA3, r)
#define RB(r) ROUND(evB, ofsB, degB, vB0, vB1, vB2, vB3, r)

        RA(0) RB(0) RA(1) RB(1)
        if (degA > 16) { RA(2) RA(3) }
        if (degB > 16) { RB(2) RB(3) }
        if (degA > 32) { RA(4) RA(5) RA(6) RA(7) }
        if (degB > 32) { RB(4) RB(5) RB(6) RB(7) }
#undef RA
#undef RB
#undef ROUND
#pragma unroll
        for (int o = 8; o <= 32; o <<= 1) {
            vA0 = pkmax_xor(vA0, o); vA1 = pkmax_xor(vA1, o);
            vA2 = pkmax_xor(vA2, o); vA3 = pkmax_xor(vA3, o);
            vB0 = pkmax_xor(vB0, o); vB1 = pkmax_xor(vB1, o);
            vB2 = pkmax_xor(vB2, o); vB3 = pkmax_xor(vB3, o);
        }
        vmA[0] = vA0; vmA[1] = vA1; vmA[2] = vA2; vmA[3] = vA3;
        vmB[0] = vB0; vmB[1] = vB1; vmB[2] = vB2; vmB[3] = vB3;
    } else {
        slow_node(rsA, reA, src_sorted, alpha_s, atA, WhH, lane, fl2, zA, vmA);
        slow_node(rsB, reB, src_sorted, alpha_s, atB, WhH, lane, fl2, zB, vmB);
    }

    // epilogue per node: h = vmax/z + bias, relu.
    float4 b0 = *(const float4*)(bias + fl2 * 8);
    float4 b1 = *(const float4*)(bias + fl2 * 8 + 4);
    float rzA = 1.0f / zA, rzB = 1.0f / zB;
    float h8A[8], h8B[8];
#pragma unroll
    for (int q = 0; q < 4; ++q) {
        float2 fa = __half22float2(*(__half2*)&vmA[q]);
        float2 fb = __half22float2(*(__half2*)&vmB[q]);
        h8A[2 * q] = fa.x; h8A[2 * q + 1] = fa.y;
        h8B[2 * q] = fb.x; h8B[2 * q + 1] = fb.y;
    }
    float bias8[8] = { b0.x, b0.y, b0.z, b0.w, b1.x, b1.y, b1.z, b1.w };
#pragma unroll
    for (int q = 0; q < 8; ++q) {
        h8A[q] = fmaxf(h8A[q] * rzA + bias8[q], 0.f);
        h8B[q] = fmaxf(h8B[q] * rzB + bias8[q], 0.f);
    }

    if (!HEAD) {
        if (g2 == 0) {
            float* op = outp + (size_t)dA * 64 + fl2 * 8;
            *(float4*)op = make_float4(h8A[0], h8A[1], h8A[2], h8A[3]);
            *(float4*)(op + 4) = make_float4(h8A[4], h8A[5], h8A[6], h8A[7]);
        } else if (g2 == 1) {
            float* op = outp + (size_t)dB * 64 + fl2 * 8;
            *(float4*)op = make_float4(h8B[0], h8B[1], h8B[2], h8B[3]);
            *(float4*)(op + 4) = make_float4(h8B[4], h8B[5], h8B[6], h8B[7]);
        }
    } else {
        if (g2 == 0) {
            float* sp = sh + (2 * w) * 64 + fl2 * 8;
            *(float4*)sp = make_float4(h8A[0], h8A[1], h8A[2], h8A[3]);
            *(float4*)(sp + 4) = make_float4(h8A[4], h8A[5], h8A[6], h8A[7]);
        } else if (g2 == 1) {
            float* sp = sh + (2 * w + 1) * 64 + fl2 * 8;
            *(float4*)sp = make_float4(h8B[0], h8B[1], h8B[2], h8B[3]);
            *(float4*)(sp + 4) = make_float4(h8B[4], h8B[5], h8B[6], h8B[7]);
        }
        __syncthreads();
#pragma unroll
        for (int n = 0; n < 2; ++n) {
            int dd = dA + n;
            const float* hrow = sh + (2 * w + n) * 64;
            float logit = -INFINITY;
            if (lane < N_CLS) {
                float acc = bo[lane];
#pragma unroll
                for (int k = 0; k < 64; ++k)
                    acc = fmaf(hrow[k], sWo[k * N_CLS + lane], acc);
                logit = acc;
            }
            float mx = logit;
#pragma unroll
            for (int o = 32; o; o >>= 1) mx = fmaxf(mx, __shfl_xor(mx, o, 64));
            float ex = (lane < N_CLS) ? __expf(logit - mx) : 0.f;
            float sm = ex;
#pragma unroll
            for (int o = 32; o; o >>= 1) sm += __shfl_xor(sm, o, 64);
            float lse = mx + __logf(sm);
            if (lane < N_CLS) outp[(size_t)dd * N_CLS + lane] = logit - lse;
        }
    }
}

extern "C" void kernel_launch(void* const* d_in, const int* in_sizes, int n_in,
                              void* d_out, int out_size, void* d_ws, size_t ws_size,
                              hipStream_t stream) {
    const float* x   = (const float*)d_in[0];
    const void*  ei  = d_in[1];
    const float* W1  = (const float*)d_in[2];
    const float* aW1 = (const float*)d_in[3];
    const float* ab1 = (const float*)d_in[4];
    const float* b1  = (const float*)d_in[5];
    const float* W2  = (const float*)d_in[6];
    const float* aW2 = (const float*)d_in[7];
    const float* ab2 = (const float*)d_in[8];
    const float* b2  = (const float*)d_in[9];
    const float* Wo  = (const float*)d_in[10];
    const float* bo  = (const float*)d_in[11];
    float* out = (float*)d_out;

    char* ws = (char*)d_ws;
    size_t off = 0;
    auto alloc = [&](size_t bytes) {
        void* p = ws + off;
        off += (bytes + 255) & ~(size_t)255;
        return p;
    };
    int2*  pairs      = (int2*)alloc((size_t)N_EDGES * 8);
    int2*  pairs_bkt  = (int2*)alloc((size_t)N_EDGES * 8);
    int*   deg        = (int*)alloc((size_t)N_NODES * 4);
    int*   rowptr     = (int*)alloc((size_t)(N_NODES + 1) * 4);
    int*   bcursor    = (int*)alloc((size_t)512 * 4);
    int*   partials   = (int*)alloc((size_t)SCAN_B * 4);
    int*   src_sorted = (int*)alloc((size_t)E_TOT * 4);
    H4*    WhH        = (H4*)alloc((size_t)N_NODES * 64 * 2);
    float* h_mid      = (float*)alloc((size_t)N_NODES * 64 * 4);
    float* alpha_s    = (float*)alloc((size_t)N_NODES * 4);
    float* alpha_t    = (float*)alloc((size_t)N_NODES * 4);

    const int B = 256;
    int gEdgeE = (N_EDGES + B - 1) / B;
    int gPassC = (N_EDGES + EPB - 1) / EPB;   // 196
    dim3 blk2(64, 4);
    int gRow  = N_NODES / 8;            // 6250, exact (2 nodes/wave)
    int gGemm = (N_NODES + 63) / 64;    // 782

    // ---- CSR build (two-level counting sort)
    hipMemsetAsync(deg, 0, (size_t)N_NODES * 4, stream);
    k_convert<<<gEdgeE, B, 0, stream>>>(ei, pairs, deg);
    k_scan1<<<N_CHUNKS, SCAN_B, 0, stream>>>(deg, rowptr, partials);
    k_scan2<<<1, SCAN_B, 0, stream>>>(partials);
    k_scan3<<<N_CHUNKS, SCAN_B, 0, stream>>>(partials, rowptr);
    k_bucket_init<<<1, 512, 0, stream>>>(rowptr, bcursor);
    k_bucket_scatter<<<gPassC, B, 0, stream>>>(pairs, bcursor, pairs_bkt);
    k_bucket_place<<<NB, B, 0, stream>>>(pairs_bkt, rowptr, src_sorted);

    // ---- layer 1
    k_gemm_alpha<128><<<gGemm, 256, 0, stream>>>(x, W1, aW1, WhH, alpha_s, alpha_t);
    k_node_aggr<0><<<gRow, blk2, 0, stream>>>(rowptr, src_sorted, alpha_s, alpha_t,
                                              ab1, WhH, b1, nullptr, nullptr, h_mid);

    // ---- layer 2 (+ fused output head)
    k_gemm_alpha<64><<<gGemm, 256, 0, stream>>>(h_mid, W2, aW2, WhH, alpha_s, alpha_t);
    k_node_aggr<1><<<gRow, blk2, 0, stream>>>(rowptr, src_sorted, alpha_s, alpha_t,
                                              ab2, WhH, b2, Wo, bo, out);
}